// Round 7
// baseline (1282.681 us; speedup 1.0000x reference)
//
#include <hip/hip_runtime.h>
#include <math.h>

#define BB 32
#define SS 65536
#define CC 20
#define NM 16
#define HH 128
#define RP 264   // k_fc0_dft DFT LDS row pitch (bf16 elems)
#define KP 136   // k_layer row pitch (bf16): 128 + 8; 272 B, 16B-aligned rows
#define WP 72    // hT/w1T row pitch (bf16): 36 dwords, b128-aligned rows
#define NSLOT 16

using short8  = __attribute__((ext_vector_type(8))) short;
using floatx4 = __attribute__((ext_vector_type(4))) float;

__device__ __forceinline__ unsigned short f2bf(float f) {
    union { float f; unsigned u; } v; v.f = f;
    unsigned u = v.u;
    return (unsigned short)((u + 0x7FFFu + ((u >> 16) & 1u)) >> 16);   // RNE
}
__device__ __forceinline__ float bf2f(unsigned short h) {
    union { unsigned u; float f; } v; v.u = ((unsigned)h) << 16; return v.f;
}
__device__ __forceinline__ unsigned pack2hi(float a, float b) {
    return (unsigned)f2bf(a) | ((unsigned)f2bf(b) << 16);
}
__device__ __forceinline__ unsigned short f2bflo(float a) {
    return f2bf(a - bf2f(f2bf(a)));
}
__device__ __forceinline__ unsigned pack2lo(float a, float b) {
    return (unsigned)f2bflo(a) | ((unsigned)f2bflo(b) << 16);
}

// Branchless gelu: erf via Abramowitz-Stegun 7.1.26 (abs err <= 1.5e-7)
__device__ __forceinline__ float gelu_fast(float v) {
    float z = fabsf(v) * 0.7071067811865476f;
    float t = __builtin_amdgcn_rcpf(1.0f + 0.3275911f * z);
    float poly = t * (0.254829592f + t * (-0.284496736f +
                 t * (1.421413741f + t * (-1.453152027f + t * 1.061405429f))));
    float e = __expf(-z * z);
    float erfz = 1.0f - poly * e;
    float se = copysignf(erfz, v);
    return 0.5f * v * (1.0f + se);
}

// ---------------- k_prep: 1/max(point_data) + zero cP (4 layers x 16 slots) --
__global__ __launch_bounds__(256) void k_prep(const float* __restrict__ pd,
                                              float* __restrict__ invmax,
                                              float* __restrict__ cP) {
    if (blockIdx.x == 0) {
        __shared__ float red[256];
        int t = threadIdx.x;
        float m = -1e30f;
        for (int i = t; i < SS; i += 256) m = fmaxf(m, pd[i]);
        red[t] = m; __syncthreads();
        for (int off = 128; off > 0; off >>= 1) {
            if (t < off) red[t] = fmaxf(red[t], red[t + off]);
            __syncthreads();
        }
        if (t == 0) invmax[0] = 1.0f / red[0];
    } else {
        int idx = (blockIdx.x - 1) * 256 + threadIdx.x;   // 1280*256 float4 = 4*16*32*640 floats
        float4 z = {0.f, 0.f, 0.f, 0.f};
        ((float4*)cP)[idx] = z;
    }
}

// ---------------- dft256: K=256 LDS-staged MFMA partial DFT (k_fc0_dft) -----
__device__ __forceinline__ void dft256(unsigned short* sh_hA, unsigned short* sh_ph,
                                       int tid, float* cPdst) {
    int wave = tid >> 6, lane = tid & 63;
    int quad = lane >> 4, frow = lane & 15;
    floatx4 acc00 = {0.f,0.f,0.f,0.f}, acc01 = {0.f,0.f,0.f,0.f};
    floatx4 acc10 = {0.f,0.f,0.f,0.f}, acc11 = {0.f,0.f,0.f,0.f};
    int kb = wave * 64 + quad * 8;
    #pragma unroll
    for (int kc = 0; kc < 2; ++kc) {
        int k = kb + kc * 32;
        short8 a0 = *(const short8*)(sh_hA + frow * RP + k);
        short8 a1 = *(const short8*)(sh_hA + (16 + frow) * RP + k);
        short8 bc = *(const short8*)(sh_ph + frow * RP + k);
        short8 bs = *(const short8*)(sh_ph + (16 + frow) * RP + k);
        acc00 = __builtin_amdgcn_mfma_f32_16x16x32_bf16(a0, bc, acc00, 0, 0, 0);
        acc01 = __builtin_amdgcn_mfma_f32_16x16x32_bf16(a0, bs, acc01, 0, 0, 0);
        acc10 = __builtin_amdgcn_mfma_f32_16x16x32_bf16(a1, bc, acc10, 0, 0, 0);
        acc11 = __builtin_amdgcn_mfma_f32_16x16x32_bf16(a1, bs, acc11, 0, 0, 0);
    }
    __syncthreads();
    float* red = (float*)sh_hA;
    #pragma unroll
    for (int r = 0; r < 4; ++r) {
        red[wave * 1024 + 0 * 256 + r * 64 + lane] = acc00[r];
        red[wave * 1024 + 1 * 256 + r * 64 + lane] = acc01[r];
        red[wave * 1024 + 2 * 256 + r * 64 + lane] = acc10[r];
        red[wave * 1024 + 3 * 256 + r * 64 + lane] = acc11[r];
    }
    __syncthreads();
    #pragma unroll
    for (int ii = 0; ii < 4; ++ii) {
        int idx = ii * 256 + tid;
        float v = red[idx] + red[1024 + idx] + red[2048 + idx] + red[3072 + idx];
        int f = idx >> 8;
        int r = (idx >> 6) & 3, ln = idx & 63;
        int o = (f >> 1) * 16 + (ln >> 4) * 4 + r;   // D row = quad*4+reg
        int m = ln & 15;                              // D col = lane&15
        if (o < CC) atomicAdd(cPdst + (f & 1) * 320 + o * 16 + m, v);
    }
}

// ---------------- k_fc0_dft: h = fc0(x,grid); DFT partials (256-s tiles) ----
__global__ __launch_bounds__(256, 4) void k_fc0_dft(const float* __restrict__ x,
        const float* __restrict__ pd, const float* __restrict__ w,
        const float* __restrict__ bias, const float* __restrict__ invmax,
        float* __restrict__ h, float* __restrict__ cP0) {
    __shared__ __align__(16) unsigned short sh_hA[32 * RP];
    __shared__ __align__(16) unsigned short sh_ph[32 * RP];
    __shared__ float lw[2 * CC], lb[CC];
    int tid = threadIdx.x;
    if (tid < 2 * CC) lw[tid] = w[tid];
    if (tid < CC) lb[tid] = bias[tid];
    {
        unsigned* z = (unsigned*)(sh_hA + CC * RP);
        for (int i = tid; i < (32 - CC) * RP / 2; i += 256) z[i] = 0;
    }
    __syncthreads();
    int b = blockIdx.y;
    int s = blockIdx.x * 256 + tid;
    float xv = x[(size_t)b * SS + s];
    float g  = pd[s] * invmax[0];
    float* hp = h + (size_t)b * CC * SS + s;
    float u = (float)s * (1.0f / 32768.0f);
    float s1, c1; sincospif(u, &s1, &c1);
    float cm = 1.0f, sm = 0.0f;
    #pragma unroll
    for (int m = 0; m < NM; ++m) {
        sh_ph[m * RP + tid]        = f2bf(cm);
        sh_ph[(16 + m) * RP + tid] = f2bf(sm);
        float cn = cm * c1 - sm * s1;
        sm = sm * c1 + cm * s1;
        cm = cn;
    }
    #pragma unroll
    for (int c = 0; c < CC; ++c) {
        float v = xv * lw[c] + g * lw[CC + c] + lb[c];
        hp[(size_t)c * SS] = v;
        sh_hA[c * RP + tid] = f2bf(v);
    }
    __syncthreads();
    dft256(sh_hA, sh_ph, tid, cP0 + ((size_t)(blockIdx.x & (NSLOT - 1)) * BB + b) * 640);
}

// ---------------- k_layer (layers 0..2): MFMA point-GEMM + gelu + DFT -------
// Augmented GEMM: out[s,o] = sum_k zA[s,k]*Waug[k,o], K=64 true (h20|cos16|
// sin16|1|0pad), hi/lo bf16 split (cols 64..127 = lo) -> 3-term MFMA.
__global__ __launch_bounds__(256, 2) void k_layer(float* __restrict__ h,
        const float* __restrict__ ww, const float* __restrict__ wb,
        const float* __restrict__ cA, const float* __restrict__ cB,
        float* __restrict__ cPn) {
    __shared__ __align__(16) unsigned short zA[128 * KP];   // 34.8 KB
    __shared__ __align__(16) unsigned short wT[32 * KP];    // 8.7 KB
    __shared__ __align__(16) unsigned short shA[32 * KP];   // 8.7 KB (DFT A)
    __shared__ __align__(16) unsigned short shP[32 * KP];   // 8.7 KB (DFT B)
    int tid = threadIdx.x;
    int b = blockIdx.y;
    int s0 = blockIdx.x * 128;
    float* hb = h + (size_t)b * CC * SS;

    // ---- build wT: Waug[k][o] transposed -> wT[o][k] (hi 0..63, lo 64..127)
    for (int idx = tid; idx < 2048; idx += 256) {
        int o = idx >> 6, k = idx & 63;
        float wf = 0.f;
        if (o < CC) {
            if (k < CC)       wf = ww[o * CC + k];
            else if (k < 36)  wf = cA[((size_t)b * CC + o) * NM + (k - 20)];
            else if (k < 52)  wf = cB[((size_t)b * CC + o) * NM + (k - 36)];
            else if (k == 52) wf = wb[o];
        }
        unsigned short hi = f2bf(wf);
        wT[o * KP + k]      = hi;
        wT[o * KP + 64 + k] = f2bf(wf - bf2f(hi));
    }
    // ---- zero shA pad rows 20..31
    {
        unsigned* z = (unsigned*)(shA + CC * KP);
        for (int i = tid; i < 12 * KP / 2; i += 256) z[i] = 0;
    }
    // ---- build zA row (2 threads per row: half 0 = hi block, half 1 = lo)
    int row = tid & 127, half = tid >> 7;
    int s = s0 + row;
    float hv[CC];
    #pragma unroll
    for (int c = 0; c < CC; ++c) hv[c] = hb[(size_t)c * SS + s];
    float u = (float)s * (1.0f / 32768.0f);
    float s1, c1; sincospif(u, &s1, &c1);
    float cmv[NM], smv[NM];
    cmv[0] = 1.0f; smv[0] = 0.0f;
    #pragma unroll
    for (int m = 1; m < NM; ++m) {
        cmv[m] = cmv[m - 1] * c1 - smv[m - 1] * s1;
        smv[m] = smv[m - 1] * c1 + cmv[m - 1] * s1;
    }
    {
        unsigned d[32];
        if (half == 0) {
            #pragma unroll
            for (int i = 0; i < 10; ++i) d[i] = pack2hi(hv[2 * i], hv[2 * i + 1]);
            #pragma unroll
            for (int i = 0; i < 8; ++i)  d[10 + i] = pack2hi(cmv[2 * i], cmv[2 * i + 1]);
            #pragma unroll
            for (int i = 0; i < 8; ++i)  d[18 + i] = pack2hi(smv[2 * i], smv[2 * i + 1]);
            d[26] = 0x00003F80u;  // col 52 = 1.0 (bias lane)
            #pragma unroll
            for (int i = 27; i < 32; ++i) d[i] = 0u;
        } else {
            #pragma unroll
            for (int i = 0; i < 10; ++i) d[i] = pack2lo(hv[2 * i], hv[2 * i + 1]);
            #pragma unroll
            for (int i = 0; i < 8; ++i)  d[10 + i] = pack2lo(cmv[2 * i], cmv[2 * i + 1]);
            #pragma unroll
            for (int i = 0; i < 8; ++i)  d[18 + i] = pack2lo(smv[2 * i], smv[2 * i + 1]);
            #pragma unroll
            for (int i = 26; i < 32; ++i) d[i] = 0u;
        }
        unsigned* dst = (unsigned*)(zA + row * KP + half * 64);
        #pragma unroll
        for (int ch = 0; ch < 8; ++ch)
            *(uint4*)(dst + ch * 4) = *(uint4*)(d + ch * 4);
    }
    // ---- DFT synthesis->analysis phasors (hi only), rows 0..15 cos / 16..31 sin
    if (half == 0) {
        #pragma unroll
        for (int m = 0; m < NM; ++m) {
            shP[m * KP + row]        = f2bf(cmv[m]);
            shP[(16 + m) * KP + row] = f2bf(smv[m]);
        }
    }
    __syncthreads();

    // ---- point-GEMM: M=128, N=32, 3-term hi/lo, 24 MFMA/wave
    int wave = tid >> 6, lane = tid & 63;
    int col = lane & 15, quad = lane >> 4;
    short8 Bhi[2][2], Blo[2][2];
    #pragma unroll
    for (int nt = 0; nt < 2; ++nt)
        #pragma unroll
        for (int kk = 0; kk < 2; ++kk) {
            Bhi[nt][kk] = *(const short8*)(wT + (nt * 16 + col) * KP + kk * 32 + quad * 8);
            Blo[nt][kk] = *(const short8*)(wT + (nt * 16 + col) * KP + 64 + kk * 32 + quad * 8);
        }
    #pragma unroll
    for (int mt = 0; mt < 2; ++mt) {
        int arow = wave * 32 + mt * 16 + col;
        short8 Ahi[2], Alo[2];
        #pragma unroll
        for (int kk = 0; kk < 2; ++kk) {
            Ahi[kk] = *(const short8*)(zA + arow * KP + kk * 32 + quad * 8);
            Alo[kk] = *(const short8*)(zA + arow * KP + 64 + kk * 32 + quad * 8);
        }
        #pragma unroll
        for (int nt = 0; nt < 2; ++nt) {
            floatx4 acc = {0.f, 0.f, 0.f, 0.f};
            #pragma unroll
            for (int kk = 0; kk < 2; ++kk) {
                acc = __builtin_amdgcn_mfma_f32_16x16x32_bf16(Ahi[kk], Bhi[nt][kk], acc, 0, 0, 0);
                acc = __builtin_amdgcn_mfma_f32_16x16x32_bf16(Ahi[kk], Blo[nt][kk], acc, 0, 0, 0);
                acc = __builtin_amdgcn_mfma_f32_16x16x32_bf16(Alo[kk], Bhi[nt][kk], acc, 0, 0, 0);
            }
            int o = nt * 16 + col;
            if (o < CC) {
                float g0 = gelu_fast(acc[0]), g1 = gelu_fast(acc[1]);
                float g2 = gelu_fast(acc[2]), g3 = gelu_fast(acc[3]);
                int sl = wave * 32 + mt * 16 + quad * 4;
                float4 st = {g0, g1, g2, g3};
                *(float4*)(hb + (size_t)o * SS + s0 + sl) = st;
                uint2 pk;
                pk.x = (unsigned)f2bf(g0) | ((unsigned)f2bf(g1) << 16);
                pk.y = (unsigned)f2bf(g2) | ((unsigned)f2bf(g3) << 16);
                *(uint2*)(shA + o * KP + sl) = pk;
            }
        }
    }
    __syncthreads();

    // ---- DFT MFMA (K=128): per wave k-chunk of 32, 4 MFMAs
    {
        int frow = col;
        int kd = wave * 32 + quad * 8;
        short8 a0 = *(const short8*)(shA + frow * KP + kd);
        short8 a1 = *(const short8*)(shA + (16 + frow) * KP + kd);
        short8 bc = *(const short8*)(shP + frow * KP + kd);
        short8 bs = *(const short8*)(shP + (16 + frow) * KP + kd);
        floatx4 acc00 = {0.f,0.f,0.f,0.f}, acc01 = {0.f,0.f,0.f,0.f};
        floatx4 acc10 = {0.f,0.f,0.f,0.f}, acc11 = {0.f,0.f,0.f,0.f};
        acc00 = __builtin_amdgcn_mfma_f32_16x16x32_bf16(a0, bc, acc00, 0, 0, 0);
        acc01 = __builtin_amdgcn_mfma_f32_16x16x32_bf16(a0, bs, acc01, 0, 0, 0);
        acc10 = __builtin_amdgcn_mfma_f32_16x16x32_bf16(a1, bc, acc10, 0, 0, 0);
        acc11 = __builtin_amdgcn_mfma_f32_16x16x32_bf16(a1, bs, acc11, 0, 0, 0);
        float* red = (float*)zA;     // zA reads done (pre-DFT sync)
        #pragma unroll
        for (int r = 0; r < 4; ++r) {
            red[wave * 1024 + 0 * 256 + r * 64 + lane] = acc00[r];
            red[wave * 1024 + 1 * 256 + r * 64 + lane] = acc01[r];
            red[wave * 1024 + 2 * 256 + r * 64 + lane] = acc10[r];
            red[wave * 1024 + 3 * 256 + r * 64 + lane] = acc11[r];
        }
    }
    __syncthreads();
    {
        float* red = (float*)zA;
        float* cPdst = cPn + ((size_t)(blockIdx.x & (NSLOT - 1)) * BB + b) * 640;
        #pragma unroll
        for (int ii = 0; ii < 4; ++ii) {
            int idx = ii * 256 + tid;
            float v = red[idx] + red[1024 + idx] + red[2048 + idx] + red[3072 + idx];
            int f = idx >> 8;
            int r = (idx >> 6) & 3, ln = idx & 63;
            int o = (f >> 1) * 16 + (ln >> 4) * 4 + r;
            int m = ln & 15;
            if (o < CC) atomicAdd(cPdst + (f & 1) * 320 + o * 16 + m, v);
        }
    }
}

// ---------------- k_mix: 16-slot partial reduce + complex mixing ------------
__global__ __launch_bounds__(320) void k_mix(const float* __restrict__ cP,
                                             const float* __restrict__ wre, const float* __restrict__ wim,
                                             float* __restrict__ cA, float* __restrict__ cB) {
    int b = blockIdx.x, tid = threadIdx.x;
    __shared__ float PQ[640];
    const float* base = cP + (size_t)b * 640;
    int i = tid >> 4, m = tid & 15;
    float sP = 0.f, sQ = 0.f;
    #pragma unroll 4
    for (int sl = 0; sl < NSLOT; ++sl) {
        sP += base[(size_t)sl * BB * 640 + tid];
        sQ += base[(size_t)sl * BB * 640 + 320 + tid];
    }
    PQ[i * 32 + m]      = sP;
    PQ[i * 32 + 16 + m] = sQ;
    __syncthreads();
    int o = i;
    float reY = 0.f, imY = 0.f;
    #pragma unroll
    for (int c = 0; c < CC; ++c) {
        float P = PQ[c * 32 + m], Q = PQ[c * 32 + 16 + m];
        float wr = wre[(size_t)(c * CC + o) * NM + m];
        float wi = wim[(size_t)(c * CC + o) * NM + m];
        reY += P * wr + Q * wi;                // X = P - iQ
        imY += P * wi - Q * wr;
    }
    const float invS = 1.0f / (float)SS;
    float a, bb;
    if (m == 0) { a = reY * invS; bb = 0.0f; } // irfft drops Im(DC)
    else        { a = 2.0f * reY * invS; bb = -2.0f * imY * invS; }
    cA[(size_t)(b * CC + o) * NM + m] = a;
    cB[(size_t)(b * CC + o) * NM + m] = bb;
}

// ---------------- k_layer_final: layer-3 point-GEMM + fc1 MFMA + gelu + fc2 -
__global__ __launch_bounds__(256, 2) void k_layer_final(const float* __restrict__ h,
        const float* __restrict__ ww, const float* __restrict__ wb,
        const float* __restrict__ cA, const float* __restrict__ cB,
        const float* __restrict__ w1, const float* __restrict__ b1,
        const float* __restrict__ w2, const float* __restrict__ b2,
        float* __restrict__ out) {
    __shared__ __align__(16) unsigned short zA[128 * KP];   // 34.8 KB; reused as hT
    __shared__ __align__(16) unsigned short wT[32 * KP];    // 8.7 KB; reused as outS
    __shared__ __align__(16) unsigned short w1T[128 * WP];  // 18.4 KB
    __shared__ float lb1[HH], lw2[HH];
    int tid = threadIdx.x;
    int b = blockIdx.y;
    int s0 = blockIdx.x * 128;
    const float* hb = h + (size_t)b * CC * SS;

    // ---- S1: build wT, w1T, lb1/lw2, zA
    for (int idx = tid; idx < 2048; idx += 256) {
        int o = idx >> 6, k = idx & 63;
        float wf = 0.f;
        if (o < CC) {
            if (k < CC)       wf = ww[o * CC + k];
            else if (k < 36)  wf = cA[((size_t)b * CC + o) * NM + (k - 20)];
            else if (k < 52)  wf = cB[((size_t)b * CC + o) * NM + (k - 36)];
            else if (k == 52) wf = wb[o];
        }
        unsigned short hi = f2bf(wf);
        wT[o * KP + k]      = hi;
        wT[o * KP + 64 + k] = f2bf(wf - bf2f(hi));
    }
    {
        unsigned* z = (unsigned*)w1T;
        for (int i = tid; i < 128 * WP / 2; i += 256) z[i] = 0;
    }
    if (tid < HH) { lb1[tid] = b1[tid]; lw2[tid] = w2[tid]; }
    int row = tid & 127, half = tid >> 7;
    int s = s0 + row;
    {
        float hv[CC];
        #pragma unroll
        for (int c = 0; c < CC; ++c) hv[c] = hb[(size_t)c * SS + s];
        float u = (float)s * (1.0f / 32768.0f);
        float s1, c1; sincospif(u, &s1, &c1);
        float cmv[NM], smv[NM];
        cmv[0] = 1.0f; smv[0] = 0.0f;
        #pragma unroll
        for (int m = 1; m < NM; ++m) {
            cmv[m] = cmv[m - 1] * c1 - smv[m - 1] * s1;
            smv[m] = smv[m - 1] * c1 + cmv[m - 1] * s1;
        }
        unsigned d[32];
        if (half == 0) {
            #pragma unroll
            for (int i = 0; i < 10; ++i) d[i] = pack2hi(hv[2 * i], hv[2 * i + 1]);
            #pragma unroll
            for (int i = 0; i < 8; ++i)  d[10 + i] = pack2hi(cmv[2 * i], cmv[2 * i + 1]);
            #pragma unroll
            for (int i = 0; i < 8; ++i)  d[18 + i] = pack2hi(smv[2 * i], smv[2 * i + 1]);
            d[26] = 0x00003F80u;
            #pragma unroll
            for (int i = 27; i < 32; ++i) d[i] = 0u;
        } else {
            #pragma unroll
            for (int i = 0; i < 10; ++i) d[i] = pack2lo(hv[2 * i], hv[2 * i + 1]);
            #pragma unroll
            for (int i = 0; i < 8; ++i)  d[10 + i] = pack2lo(cmv[2 * i], cmv[2 * i + 1]);
            #pragma unroll
            for (int i = 0; i < 8; ++i)  d[18 + i] = pack2lo(smv[2 * i], smv[2 * i + 1]);
            #pragma unroll
            for (int i = 26; i < 32; ++i) d[i] = 0u;
        }
        unsigned* dst = (unsigned*)(zA + row * KP + half * 64);
        #pragma unroll
        for (int ch = 0; ch < 8; ++ch)
            *(uint4*)(dst + ch * 4) = *(uint4*)(d + ch * 4);
    }
    // w1T fill (after zero: same phase is fine — zero loop above touches all
    // of w1T, fill overwrites cols 0..19/32..51; both pre-sync, same thread
    // ordering hazard: zero and fill race across threads! Do fill after sync.
    __syncthreads();
    for (int idx = tid; idx < CC * HH; idx += 256) {
        int c = idx / HH, j = idx - c * HH;       // w1[c][j]
        float v = w1[idx];
        unsigned short hi = f2bf(v);
        w1T[j * WP + c]      = hi;
        w1T[j * WP + 32 + c] = f2bflo(v);
    }

    // ---- S2: point-GEMM (no gelu), keep acc
    int wave = tid >> 6, lane = tid & 63;
    int col = lane & 15, quad = lane >> 4;
    floatx4 accA[2][2];
    {
        short8 Bhi[2][2], Blo[2][2];
        #pragma unroll
        for (int nt = 0; nt < 2; ++nt)
            #pragma unroll
            for (int kk = 0; kk < 2; ++kk) {
                Bhi[nt][kk] = *(const short8*)(wT + (nt * 16 + col) * KP + kk * 32 + quad * 8);
                Blo[nt][kk] = *(const short8*)(wT + (nt * 16 + col) * KP + 64 + kk * 32 + quad * 8);
            }
        #pragma unroll
        for (int mt = 0; mt < 2; ++mt) {
            int arow = wave * 32 + mt * 16 + col;
            short8 Ahi[2], Alo[2];
            #pragma unroll
            for (int kk = 0; kk < 2; ++kk) {
                Ahi[kk] = *(const short8*)(zA + arow * KP + kk * 32 + quad * 8);
                Alo[kk] = *(const short8*)(zA + arow * KP + 64 + kk * 32 + quad * 8);
            }
            #pragma unroll
            for (int nt = 0; nt < 2; ++nt) {
                floatx4 acc = {0.f, 0.f, 0.f, 0.f};
                #pragma unroll
                for (int kk = 0; kk < 2; ++kk) {
                    acc = __builtin_amdgcn_mfma_f32_16x16x32_bf16(Ahi[kk], Bhi[nt][kk], acc, 0, 0, 0);
                    acc = __builtin_amdgcn_mfma_f32_16x16x32_bf16(Ahi[kk], Blo[nt][kk], acc, 0, 0, 0);
                    acc = __builtin_amdgcn_mfma_f32_16x16x32_bf16(Alo[kk], Bhi[nt][kk], acc, 0, 0, 0);
                }
                accA[mt][nt] = acc;
            }
        }
    }
    __syncthreads();
    // ---- S2b: zero hT (overlays zA)
    unsigned short* hT = zA;
    {
        unsigned* z = (unsigned*)hT;
        for (int i = tid; i < 128 * WP / 2; i += 256) z[i] = 0;
    }
    __syncthreads();
    // ---- S3: scatter point output into hT (hi/lo)
    #pragma unroll
    for (int mt = 0; mt < 2; ++mt)
        #pragma unroll
        for (int nt = 0; nt < 2; ++nt) {
            int o = nt * 16 + col;
            if (o < CC) {
                #pragma unroll
                for (int r = 0; r < 4; ++r) {
                    int srow = wave * 32 + mt * 16 + quad * 4 + r;
                    float v = accA[mt][nt][r];
                    unsigned short hi = f2bf(v);
                    hT[srow * WP + o]      = hi;
                    hT[srow * WP + 32 + o] = f2bflo(v);
                }
            }
        }
    __syncthreads();
    // ---- S4: fc1 MFMA (hi/lo) + gelu + fc2
    float* outS = (float*)wT;
    {
        short8 bhi[8], blo[8];
        #pragma unroll
        for (int nt = 0; nt < 8; ++nt) {
            bhi[nt] = *(const short8*)(w1T + (nt * 16 + col) * WP + quad * 8);
            blo[nt] = *(const short8*)(w1T + (nt * 16 + col) * WP + 32 + quad * 8);
        }
        float lb1r[8], w2r[8];
        #pragma unroll
        for (int nt = 0; nt < 8; ++nt) { lb1r[nt] = lb1[nt * 16 + col]; w2r[nt] = lw2[nt * 16 + col]; }
        float b2v = b2[0];
        #pragma unroll
        for (int mt = 0; mt < 2; ++mt) {
            int srow = wave * 32 + mt * 16 + col;
            short8 ahi = *(const short8*)(hT + srow * WP + quad * 8);
            short8 alo = *(const short8*)(hT + srow * WP + 32 + quad * 8);
            float part[4] = {0.f, 0.f, 0.f, 0.f};
            #pragma unroll
            for (int nt = 0; nt < 8; ++nt) {
                floatx4 a = {0.f, 0.f, 0.f, 0.f};
                a = __builtin_amdgcn_mfma_f32_16x16x32_bf16(ahi, bhi[nt], a, 0, 0, 0);
                a = __builtin_amdgcn_mfma_f32_16x16x32_bf16(ahi, blo[nt], a, 0, 0, 0);
                a = __builtin_amdgcn_mfma_f32_16x16x32_bf16(alo, bhi[nt], a, 0, 0, 0);
                #pragma unroll
                for (int r = 0; r < 4; ++r) {
                    float t = gelu_fast(a[r] + lb1r[nt]);
                    part[r] += t * w2r[nt];
                }
            }
            #pragma unroll
            for (int r = 0; r < 4; ++r) {
                float p = part[r];
                p += __shfl_xor(p, 1, 64);
                p += __shfl_xor(p, 2, 64);
                p += __shfl_xor(p, 4, 64);
                p += __shfl_xor(p, 8, 64);
                if (col == 0) outS[wave * 32 + mt * 16 + quad * 4 + r] = p + b2v;
            }
        }
    }
    __syncthreads();
    if (tid < 128) out[(size_t)b * SS + s0 + tid] = outS[tid];
}

extern "C" void kernel_launch(void* const* d_in, const int* in_sizes, int n_in,
                              void* d_out, int out_size, void* d_ws, size_t ws_size,
                              hipStream_t stream) {
    (void)in_sizes; (void)n_in; (void)out_size; (void)ws_size;
    const float* x    = (const float*)d_in[0];
    const float* pd   = (const float*)d_in[1];
    const float* fc0w = (const float*)d_in[2];
    const float* fc0b = (const float*)d_in[3];
    const float* fc1w = (const float*)d_in[4];
    const float* fc1b = (const float*)d_in[5];
    const float* fc2w = (const float*)d_in[6];
    const float* fc2b = (const float*)d_in[7];

    char* ws = (char*)d_ws;
    float* h = (float*)ws;
    size_t off = (size_t)BB * CC * SS * 4;                            // 167.8 MB
    float* cP = (float*)(ws + off); off += (size_t)4 * NSLOT * BB * 640 * 4;  // 5.24 MB
    float* cA = (float*)(ws + off); off += (size_t)BB * CC * NM * 4;
    float* cB = (float*)(ws + off); off += (size_t)BB * CC * NM * 4;
    float* invmax = (float*)(ws + off); off += 256;
    const size_t CPL = (size_t)NSLOT * BB * 640;   // floats per layer-slot set

    k_prep<<<1281, 256, 0, stream>>>(pd, invmax, cP);
    k_fc0_dft<<<dim3(256, 32), 256, 0, stream>>>(x, pd, fc0w, fc0b, invmax, h, cP);

    for (int l = 0; l < 3; ++l) {
        const float* wre = (const float*)d_in[8 + 4 * l];
        const float* wim = (const float*)d_in[9 + 4 * l];
        const float* ww  = (const float*)d_in[10 + 4 * l];
        const float* wb  = (const float*)d_in[11 + 4 * l];
        k_mix<<<BB, 320, 0, stream>>>(cP + (size_t)l * CPL, wre, wim, cA, cB);
        k_layer<<<dim3(512, 32), 256, 0, stream>>>(h, ww, wb, cA, cB,
                                                   cP + (size_t)(l + 1) * CPL);
    }
    {
        const float* wre = (const float*)d_in[20];
        const float* wim = (const float*)d_in[21];
        const float* ww  = (const float*)d_in[22];
        const float* wb  = (const float*)d_in[23];
        k_mix<<<BB, 320, 0, stream>>>(cP + (size_t)3 * CPL, wre, wim, cA, cB);
        k_layer_final<<<dim3(512, 32), 256, 0, stream>>>(h, ww, wb, cA, cB,
                                                         fc1w, fc1b, fc2w, fc2b,
                                                         (float*)d_out);
    }
}

// Round 8
// 958.173 us; speedup vs baseline: 1.3387x; 1.3387x over previous
//
#include <hip/hip_runtime.h>
#include <math.h>

#define BB 32
#define SS 65536
#define CC 20
#define NM 16
#define HH 128
#define RP 264   // DFT LDS row pitch (bf16 elems)
#define WP 72    // hT row pitch (bf16 elems): 36 dwords; b128-aligned rows
#define NSLOT 16

using short8  = __attribute__((ext_vector_type(8))) short;
using floatx4 = __attribute__((ext_vector_type(4))) float;

__device__ __forceinline__ unsigned short f2bf(float f) {
    union { float f; unsigned u; } v; v.f = f;
    unsigned u = v.u;
    return (unsigned short)((u + 0x7FFFu + ((u >> 16) & 1u)) >> 16);   // RNE
}
__device__ __forceinline__ float bf2f(unsigned short h) {
    union { unsigned u; float f; } v; v.u = ((unsigned)h) << 16; return v.f;
}
__device__ __forceinline__ unsigned short f2bflo(float a) {
    return f2bf(a - bf2f(f2bf(a)));
}

// Branchless gelu: erf via Abramowitz-Stegun 7.1.26 (abs err <= 1.5e-7)
__device__ __forceinline__ float gelu_fast(float v) {
    float z = fabsf(v) * 0.7071067811865476f;
    float t = __builtin_amdgcn_rcpf(1.0f + 0.3275911f * z);
    float poly = t * (0.254829592f + t * (-0.284496736f +
                 t * (1.421413741f + t * (-1.453152027f + t * 1.061405429f))));
    float e = __expf(-z * z);
    float erfz = 1.0f - poly * e;
    float se = copysignf(erfz, v);
    return 0.5f * v * (1.0f + se);
}

// ---------------- k_prep: max-reduce + zero cP + build w1T(global) ----------
// grid 1282: block 0 = 1/max(pd); 1..1280 zero cP; 1281 builds w1Tg.
// w1Tg[j*64+k]: k<20 -> bf16-hi of w1[k][j]; 32<=k<52 -> bf16-lo of w1[k-32][j];
// else 0.  (fc1 B-operand, transposed, hi/lo split, L2-resident 16 KB)
__global__ __launch_bounds__(256) void k_prep(const float* __restrict__ pd,
                                              const float* __restrict__ w1,
                                              float* __restrict__ invmax,
                                              float* __restrict__ cP,
                                              unsigned short* __restrict__ w1Tg) {
    int bx = blockIdx.x;
    if (bx == 0) {
        __shared__ float red[256];
        int t = threadIdx.x;
        float m = -1e30f;
        for (int i = t; i < SS; i += 256) m = fmaxf(m, pd[i]);
        red[t] = m; __syncthreads();
        for (int off = 128; off > 0; off >>= 1) {
            if (t < off) red[t] = fmaxf(red[t], red[t + off]);
            __syncthreads();
        }
        if (t == 0) invmax[0] = 1.0f / red[0];
    } else if (bx <= 1280) {
        int idx = (bx - 1) * 256 + threadIdx.x;   // 1280*256 float4 = 4*16*32*640 floats
        float4 z = {0.f, 0.f, 0.f, 0.f};
        ((float4*)cP)[idx] = z;
    } else {
        for (int idx = threadIdx.x; idx < HH * 64; idx += 256) {
            int j = idx >> 6, k = idx & 63;
            unsigned short r = 0;
            if (k < CC) r = f2bf(w1[k * HH + j]);
            else if (k >= 32 && k < 32 + CC) r = f2bflo(w1[(k - 32) * HH + j]);
            w1Tg[idx] = r;
        }
    }
}

// ---------------- shared DFT tail: LDS-staged MFMA partial DFT --------------
__device__ __forceinline__ void dft_phase(unsigned short* sh_hA, unsigned short* sh_ph,
                                          int tid, float* cPdst) {
    int wave = tid >> 6, lane = tid & 63;
    int quad = lane >> 4, frow = lane & 15;
    floatx4 acc00 = {0.f,0.f,0.f,0.f}, acc01 = {0.f,0.f,0.f,0.f};
    floatx4 acc10 = {0.f,0.f,0.f,0.f}, acc11 = {0.f,0.f,0.f,0.f};
    int kb = wave * 64 + quad * 8;
    #pragma unroll
    for (int kc = 0; kc < 2; ++kc) {
        int k = kb + kc * 32;
        short8 a0 = *(const short8*)(sh_hA + frow * RP + k);
        short8 a1 = *(const short8*)(sh_hA + (16 + frow) * RP + k);
        short8 bc = *(const short8*)(sh_ph + frow * RP + k);
        short8 bs = *(const short8*)(sh_ph + (16 + frow) * RP + k);
        acc00 = __builtin_amdgcn_mfma_f32_16x16x32_bf16(a0, bc, acc00, 0, 0, 0);
        acc01 = __builtin_amdgcn_mfma_f32_16x16x32_bf16(a0, bs, acc01, 0, 0, 0);
        acc10 = __builtin_amdgcn_mfma_f32_16x16x32_bf16(a1, bc, acc10, 0, 0, 0);
        acc11 = __builtin_amdgcn_mfma_f32_16x16x32_bf16(a1, bs, acc11, 0, 0, 0);
    }
    __syncthreads();
    float* red = (float*)sh_hA;
    #pragma unroll
    for (int r = 0; r < 4; ++r) {
        red[wave * 1024 + 0 * 256 + r * 64 + lane] = acc00[r];
        red[wave * 1024 + 1 * 256 + r * 64 + lane] = acc01[r];
        red[wave * 1024 + 2 * 256 + r * 64 + lane] = acc10[r];
        red[wave * 1024 + 3 * 256 + r * 64 + lane] = acc11[r];
    }
    __syncthreads();
    #pragma unroll
    for (int ii = 0; ii < 4; ++ii) {
        int idx = ii * 256 + tid;
        float v = red[idx] + red[1024 + idx] + red[2048 + idx] + red[3072 + idx];
        int f = idx >> 8;
        int r = (idx >> 6) & 3, ln = idx & 63;
        int o = (f >> 1) * 16 + (ln >> 4) * 4 + r;   // D row = quad*4+reg
        int m = ln & 15;                              // D col = lane&15
        if (o < CC) atomicAdd(cPdst + (f & 1) * 320 + o * 16 + m, v);
    }
}

// ---------------- k_fc0_dft ----------------
__global__ __launch_bounds__(256, 4) void k_fc0_dft(const float* __restrict__ x,
        const float* __restrict__ pd, const float* __restrict__ w,
        const float* __restrict__ bias, const float* __restrict__ invmax,
        float* __restrict__ h, float* __restrict__ cP0) {
    __shared__ __align__(16) unsigned short sh_hA[32 * RP];
    __shared__ __align__(16) unsigned short sh_ph[32 * RP];
    __shared__ float lw[2 * CC], lb[CC];
    int tid = threadIdx.x;
    if (tid < 2 * CC) lw[tid] = w[tid];
    if (tid < CC) lb[tid] = bias[tid];
    {
        unsigned* z = (unsigned*)(sh_hA + CC * RP);
        for (int i = tid; i < (32 - CC) * RP / 2; i += 256) z[i] = 0;
    }
    __syncthreads();
    int b = blockIdx.y;
    int s = blockIdx.x * 256 + tid;
    float xv = x[(size_t)b * SS + s];
    float g  = pd[s] * invmax[0];
    float* hp = h + (size_t)b * CC * SS + s;
    float u = (float)s * (1.0f / 32768.0f);
    float s1, c1; sincospif(u, &s1, &c1);
    float cm = 1.0f, sm = 0.0f;
    #pragma unroll
    for (int m = 0; m < NM; ++m) {
        sh_ph[m * RP + tid]        = f2bf(cm);
        sh_ph[(16 + m) * RP + tid] = f2bf(sm);
        float cn = cm * c1 - sm * s1;
        sm = sm * c1 + cm * s1;
        cm = cn;
    }
    #pragma unroll
    for (int c = 0; c < CC; ++c) {
        float v = xv * lw[c] + g * lw[CC + c] + lb[c];
        hp[(size_t)c * SS] = v;
        sh_hA[c * RP + tid] = f2bf(v);
    }
    __syncthreads();
    dft_phase(sh_hA, sh_ph, tid, cP0 + ((size_t)(blockIdx.x & (NSLOT - 1)) * BB + b) * 640);
}

// ---------------- k_point_dft (layers 0..2: gelu + next-layer DFT) ----------
// (256,4): LDS 38.7 KB fits 4 blocks/CU; VGPR cap 128 vs ~90 live (no spill;
// R2's spill was a 64-reg cap — watch WRITE_SIZE to confirm).
__global__ __launch_bounds__(256, 4) void k_point_dft(float* __restrict__ h,
        const float* __restrict__ ww, const float* __restrict__ wb,
        const float* __restrict__ cA, const float* __restrict__ cB,
        float* __restrict__ cPn) {
    __shared__ __align__(16) unsigned short sh_hA[32 * RP];
    __shared__ __align__(16) unsigned short sh_ph[32 * RP];
    __shared__ float lww[CC * CC], lwb[CC], lA[CC * NM], lB[CC * NM];
    int tid = threadIdx.x;
    int b = blockIdx.y;
    for (int i = tid; i < CC * CC; i += 256) lww[i] = ww[i];
    if (tid < CC) lwb[tid] = wb[tid];
    for (int i = tid; i < CC * NM; i += 256) { lA[i] = cA[b * CC * NM + i]; lB[i] = cB[b * CC * NM + i]; }
    {
        unsigned* z = (unsigned*)(sh_hA + CC * RP);
        for (int i = tid; i < (32 - CC) * RP / 2; i += 256) z[i] = 0;
    }
    __syncthreads();
    int s = blockIdx.x * 256 + tid;
    float* hp = h + (size_t)b * CC * SS + s;
    float u = (float)s * (1.0f / 32768.0f);
    float s1, c1; sincospif(u, &s1, &c1);
    float cm[NM], sm[NM];
    cm[0] = 1.0f; sm[0] = 0.0f;
    #pragma unroll
    for (int m = 1; m < NM; ++m) {
        cm[m] = cm[m - 1] * c1 - sm[m - 1] * s1;
        sm[m] = sm[m - 1] * c1 + cm[m - 1] * s1;
    }
    #pragma unroll
    for (int m = 0; m < NM; ++m) {
        sh_ph[m * RP + tid]        = f2bf(cm[m]);
        sh_ph[(16 + m) * RP + tid] = f2bf(sm[m]);
    }
    float hv[CC];
    #pragma unroll
    for (int c = 0; c < CC; ++c) hv[c] = hp[(size_t)c * SS];
    #pragma unroll 2
    for (int o = 0; o < CC; ++o) {
        float a = lwb[o];
        #pragma unroll
        for (int c = 0; c < CC; ++c) a += lww[o * CC + c] * hv[c];
        #pragma unroll
        for (int m = 0; m < NM; ++m)
            a += lA[o * NM + m] * cm[m] + lB[o * NM + m] * sm[m];
        a = gelu_fast(a);
        hp[(size_t)o * SS] = a;
        sh_hA[o * RP + tid] = f2bf(a);
    }
    __syncthreads();
    dft_phase(sh_hA, sh_ph, tid, cPn + ((size_t)(blockIdx.x & (NSLOT - 1)) * BB + b) * 640);
}

// ---------------- k_mix: 16-slot partial reduce + complex mixing ------------
__global__ __launch_bounds__(320) void k_mix(const float* __restrict__ cP,
                                             const float* __restrict__ wre, const float* __restrict__ wim,
                                             float* __restrict__ cA, float* __restrict__ cB) {
    int b = blockIdx.x, tid = threadIdx.x;
    __shared__ float PQ[640];
    const float* base = cP + (size_t)b * 640;
    int i = tid >> 4, m = tid & 15;
    float sP = 0.f, sQ = 0.f;
    #pragma unroll 4
    for (int sl = 0; sl < NSLOT; ++sl) {
        sP += base[(size_t)sl * BB * 640 + tid];
        sQ += base[(size_t)sl * BB * 640 + 320 + tid];
    }
    PQ[i * 32 + m]      = sP;
    PQ[i * 32 + 16 + m] = sQ;
    __syncthreads();
    int o = i;
    float reY = 0.f, imY = 0.f;
    #pragma unroll
    for (int c = 0; c < CC; ++c) {
        float P = PQ[c * 32 + m], Q = PQ[c * 32 + 16 + m];
        float wr = wre[(size_t)(c * CC + o) * NM + m];
        float wi = wim[(size_t)(c * CC + o) * NM + m];
        reY += P * wr + Q * wi;                // X = P - iQ
        imY += P * wi - Q * wr;
    }
    const float invS = 1.0f / (float)SS;
    float a, bb;
    if (m == 0) { a = reY * invS; bb = 0.0f; } // irfft drops Im(DC)
    else        { a = 2.0f * reY * invS; bb = -2.0f * imY * invS; }
    cA[(size_t)(b * CC + o) * NM + m] = a;
    cB[(size_t)(b * CC + o) * NM + m] = bb;
}

// ---------------- k_point_final: layer-3 point op + fc1 MFMA + gelu + fc2 ---
// w1T comes from GLOBAL (precomputed in k_prep) -> LDS drops 62->43 KB ->
// 3 blocks/CU at (256,3). B-fragments loaded early to hide L2 latency under
// the point-op. Full o-unroll mandatory (R5 lesson: dynamic reg-array index
// demotes rowf to scratch).
__global__ __launch_bounds__(256, 3) void k_point_final(const float* __restrict__ h,
        const float* __restrict__ ww, const float* __restrict__ wb,
        const float* __restrict__ cA, const float* __restrict__ cB,
        const unsigned short* __restrict__ w1Tg, const float* __restrict__ b1,
        const float* __restrict__ w2, const float* __restrict__ b2,
        float* __restrict__ out) {
    __shared__ __align__(16) unsigned short hT[256 * WP];   // 36.9 KB
    __shared__ float lww[CC * CC], lwb[CC], lA[CC * NM], lB[CC * NM];
    __shared__ float lb1[HH], lw2[HH], outS[256];
    int tid = threadIdx.x;
    int b = blockIdx.y;
    for (int i = tid; i < CC * CC; i += 256) lww[i] = ww[i];
    if (tid < CC) lwb[tid] = wb[tid];
    for (int i = tid; i < CC * NM; i += 256) { lA[i] = cA[b * CC * NM + i]; lB[i] = cB[b * CC * NM + i]; }
    if (tid < HH) { lb1[tid] = b1[tid]; lw2[tid] = w2[tid]; }
    __syncthreads();

    int wave = tid >> 6, lane = tid & 63;
    int col = lane & 15, quad = lane >> 4;
    // early fc1 B-fragment loads (global, L2-resident) — overlap with point-op
    short8 bhi[8], blo[8];
    #pragma unroll
    for (int nt = 0; nt < 8; ++nt) {
        bhi[nt] = *(const short8*)(w1Tg + (size_t)(nt * 16 + col) * 64 + quad * 8);
        blo[nt] = *(const short8*)(w1Tg + (size_t)(nt * 16 + col) * 64 + 32 + quad * 8);
    }

    // point op (layer 3, no gelu), pack own hT row
    int s = blockIdx.x * 256 + tid;
    const float* hp = h + (size_t)b * CC * SS + s;
    float u = (float)s * (1.0f / 32768.0f);
    float s1, c1; sincospif(u, &s1, &c1);
    float cm[NM], sm[NM];
    cm[0] = 1.0f; sm[0] = 0.0f;
    #pragma unroll
    for (int m = 1; m < NM; ++m) {
        cm[m] = cm[m - 1] * c1 - sm[m - 1] * s1;
        sm[m] = sm[m - 1] * c1 + cm[m - 1] * s1;
    }
    float hv[CC];
    #pragma unroll
    for (int c = 0; c < CC; ++c) hv[c] = hp[(size_t)c * SS];
    short8 rowf[8];
    #pragma unroll
    for (int ch = 0; ch < 8; ++ch) rowf[ch] = (short8){0,0,0,0,0,0,0,0};
    #pragma unroll        // FULL unroll required (R5 scratch lesson)
    for (int o = 0; o < CC; ++o) {
        float a = lwb[o];
        #pragma unroll
        for (int c = 0; c < CC; ++c) a += lww[o * CC + c] * hv[c];
        #pragma unroll
        for (int m = 0; m < NM; ++m)
            a += lA[o * NM + m] * cm[m] + lB[o * NM + m] * sm[m];
        unsigned short hi = f2bf(a);
        rowf[o >> 3][o & 7]       = (short)hi;
        rowf[4 + (o >> 3)][o & 7] = (short)f2bf(a - bf2f(hi));
    }
    #pragma unroll
    for (int ch = 0; ch < 8; ++ch)
        *(short8*)(hT + tid * WP + ch * 8) = rowf[ch];
    __syncthreads();

    // fc1 MFMA (hi/lo) + gelu + fc2
    float lb1r[8], w2r[8];
    #pragma unroll
    for (int nt = 0; nt < 8; ++nt) { lb1r[nt] = lb1[nt * 16 + col]; w2r[nt] = lw2[nt * 16 + col]; }
    float b2v = b2[0];
    #pragma unroll
    for (int mt = 0; mt < 4; ++mt) {
        int srow = wave * 64 + mt * 16 + col;     // A row m = lane&15
        short8 ahi = *(const short8*)(hT + srow * WP + quad * 8);
        short8 alo = *(const short8*)(hT + srow * WP + 32 + quad * 8);
        float part[4] = {0.f, 0.f, 0.f, 0.f};
        #pragma unroll
        for (int nt = 0; nt < 8; ++nt) {
            floatx4 a = {0.f, 0.f, 0.f, 0.f};
            a = __builtin_amdgcn_mfma_f32_16x16x32_bf16(ahi, bhi[nt], a, 0, 0, 0);
            a = __builtin_amdgcn_mfma_f32_16x16x32_bf16(ahi, blo[nt], a, 0, 0, 0);
            a = __builtin_amdgcn_mfma_f32_16x16x32_bf16(alo, bhi[nt], a, 0, 0, 0);
            #pragma unroll
            for (int r = 0; r < 4; ++r) {
                float t = gelu_fast(a[r] + lb1r[nt]);
                part[r] += t * w2r[nt];
            }
        }
        #pragma unroll
        for (int r = 0; r < 4; ++r) {
            float p = part[r];
            p += __shfl_xor(p, 1, 64);
            p += __shfl_xor(p, 2, 64);
            p += __shfl_xor(p, 4, 64);
            p += __shfl_xor(p, 8, 64);
            if (col == 0) outS[wave * 64 + mt * 16 + quad * 4 + r] = p + b2v;
        }
    }
    __syncthreads();
    out[(size_t)b * SS + blockIdx.x * 256 + tid] = outS[tid];
}

extern "C" void kernel_launch(void* const* d_in, const int* in_sizes, int n_in,
                              void* d_out, int out_size, void* d_ws, size_t ws_size,
                              hipStream_t stream) {
    (void)in_sizes; (void)n_in; (void)out_size; (void)ws_size;
    const float* x    = (const float*)d_in[0];
    const float* pd   = (const float*)d_in[1];
    const float* fc0w = (const float*)d_in[2];
    const float* fc0b = (const float*)d_in[3];
    const float* fc1w = (const float*)d_in[4];
    const float* fc1b = (const float*)d_in[5];
    const float* fc2w = (const float*)d_in[6];
    const float* fc2b = (const float*)d_in[7];

    char* ws = (char*)d_ws;
    float* h = (float*)ws;
    size_t off = (size_t)BB * CC * SS * 4;                            // 167.8 MB
    float* cP = (float*)(ws + off); off += (size_t)4 * NSLOT * BB * 640 * 4;  // 5.24 MB
    float* cA = (float*)(ws + off); off += (size_t)BB * CC * NM * 4;
    float* cB = (float*)(ws + off); off += (size_t)BB * CC * NM * 4;
    float* invmax = (float*)(ws + off); off += 256;
    unsigned short* w1Tg = (unsigned short*)(ws + off); off += (size_t)HH * 64 * 2;  // 16 KB
    const size_t CPL = (size_t)NSLOT * BB * 640;   // floats per layer-slot set

    dim3 gBS(SS / 256, BB);

    k_prep<<<1282, 256, 0, stream>>>(pd, fc1w, invmax, cP, w1Tg);
    k_fc0_dft<<<gBS, 256, 0, stream>>>(x, pd, fc0w, fc0b, invmax, h, cP);

    for (int l = 0; l < 3; ++l) {
        const float* wre = (const float*)d_in[8 + 4 * l];
        const float* wim = (const float*)d_in[9 + 4 * l];
        const float* ww  = (const float*)d_in[10 + 4 * l];
        const float* wb  = (const float*)d_in[11 + 4 * l];
        k_mix<<<BB, 320, 0, stream>>>(cP + (size_t)l * CPL, wre, wim, cA, cB);
        k_point_dft<<<gBS, 256, 0, stream>>>(h, ww, wb, cA, cB,
                                             cP + (size_t)(l + 1) * CPL);
    }
    {   // layer 3 fused with fc1/gelu/fc2
        const float* wre = (const float*)d_in[20];
        const float* wim = (const float*)d_in[21];
        const float* ww  = (const float*)d_in[22];
        const float* wb  = (const float*)d_in[23];
        k_mix<<<BB, 320, 0, stream>>>(cP + (size_t)3 * CPL, wre, wim, cA, cB);
        k_point_final<<<gBS, 256, 0, stream>>>(h, ww, wb, cA, cB,
                                               w1Tg, fc1b, fc2w, fc2b, (float*)d_out);
    }
}

// Round 9
// 944.354 us; speedup vs baseline: 1.3583x; 1.0146x over previous
//
#include <hip/hip_runtime.h>
#include <math.h>

#define BB 32
#define SS 65536
#define CC 20
#define NM 16
#define HH 128
#define RP 264   // DFT LDS row pitch (bf16 elems)
#define WP 72    // hT row pitch (bf16 elems): 36 dwords; b128-aligned rows
#define NSLOT 16

using short8  = __attribute__((ext_vector_type(8))) short;
using floatx4 = __attribute__((ext_vector_type(4))) float;

__device__ __forceinline__ unsigned short f2bf(float f) {
    union { float f; unsigned u; } v; v.f = f;
    unsigned u = v.u;
    return (unsigned short)((u + 0x7FFFu + ((u >> 16) & 1u)) >> 16);   // RNE
}
__device__ __forceinline__ float bf2f(unsigned short h) {
    union { unsigned u; float f; } v; v.u = ((unsigned)h) << 16; return v.f;
}
__device__ __forceinline__ unsigned short f2bflo(float a) {
    return f2bf(a - bf2f(f2bf(a)));
}

// Branchless gelu: erf via Abramowitz-Stegun 7.1.26 (abs err <= 1.5e-7)
__device__ __forceinline__ float gelu_fast(float v) {
    float z = fabsf(v) * 0.7071067811865476f;
    float t = __builtin_amdgcn_rcpf(1.0f + 0.3275911f * z);
    float poly = t * (0.254829592f + t * (-0.284496736f +
                 t * (1.421413741f + t * (-1.453152027f + t * 1.061405429f))));
    float e = __expf(-z * z);
    float erfz = 1.0f - poly * e;
    float se = copysignf(erfz, v);
    return 0.5f * v * (1.0f + se);
}

// ---------------- k_prep: max-reduce + zero cP + build w1T(global) ----------
__global__ __launch_bounds__(256) void k_prep(const float* __restrict__ pd,
                                              const float* __restrict__ w1,
                                              float* __restrict__ invmax,
                                              float* __restrict__ cP,
                                              unsigned short* __restrict__ w1Tg) {
    int bx = blockIdx.x;
    if (bx == 0) {
        __shared__ float red[256];
        int t = threadIdx.x;
        float m = -1e30f;
        for (int i = t; i < SS; i += 256) m = fmaxf(m, pd[i]);
        red[t] = m; __syncthreads();
        for (int off = 128; off > 0; off >>= 1) {
            if (t < off) red[t] = fmaxf(red[t], red[t + off]);
            __syncthreads();
        }
        if (t == 0) invmax[0] = 1.0f / red[0];
    } else if (bx <= 1280) {
        int idx = (bx - 1) * 256 + threadIdx.x;   // 1280*256 float4 = 4*16*32*640 floats
        float4 z = {0.f, 0.f, 0.f, 0.f};
        ((float4*)cP)[idx] = z;
    } else {
        for (int idx = threadIdx.x; idx < HH * 64; idx += 256) {
            int j = idx >> 6, k = idx & 63;
            unsigned short r = 0;
            if (k < CC) r = f2bf(w1[k * HH + j]);
            else if (k >= 32 && k < 32 + CC) r = f2bflo(w1[(k - 32) * HH + j]);
            w1Tg[idx] = r;
        }
    }
}

// ---------------- shared DFT tail: LDS-staged MFMA partial DFT --------------
__device__ __forceinline__ void dft_phase(unsigned short* sh_hA, unsigned short* sh_ph,
                                          int tid, float* cPdst) {
    int wave = tid >> 6, lane = tid & 63;
    int quad = lane >> 4, frow = lane & 15;
    floatx4 acc00 = {0.f,0.f,0.f,0.f}, acc01 = {0.f,0.f,0.f,0.f};
    floatx4 acc10 = {0.f,0.f,0.f,0.f}, acc11 = {0.f,0.f,0.f,0.f};
    int kb = wave * 64 + quad * 8;
    #pragma unroll
    for (int kc = 0; kc < 2; ++kc) {
        int k = kb + kc * 32;
        short8 a0 = *(const short8*)(sh_hA + frow * RP + k);
        short8 a1 = *(const short8*)(sh_hA + (16 + frow) * RP + k);
        short8 bc = *(const short8*)(sh_ph + frow * RP + k);
        short8 bs = *(const short8*)(sh_ph + (16 + frow) * RP + k);
        acc00 = __builtin_amdgcn_mfma_f32_16x16x32_bf16(a0, bc, acc00, 0, 0, 0);
        acc01 = __builtin_amdgcn_mfma_f32_16x16x32_bf16(a0, bs, acc01, 0, 0, 0);
        acc10 = __builtin_amdgcn_mfma_f32_16x16x32_bf16(a1, bc, acc10, 0, 0, 0);
        acc11 = __builtin_amdgcn_mfma_f32_16x16x32_bf16(a1, bs, acc11, 0, 0, 0);
    }
    __syncthreads();
    float* red = (float*)sh_hA;
    #pragma unroll
    for (int r = 0; r < 4; ++r) {
        red[wave * 1024 + 0 * 256 + r * 64 + lane] = acc00[r];
        red[wave * 1024 + 1 * 256 + r * 64 + lane] = acc01[r];
        red[wave * 1024 + 2 * 256 + r * 64 + lane] = acc10[r];
        red[wave * 1024 + 3 * 256 + r * 64 + lane] = acc11[r];
    }
    __syncthreads();
    #pragma unroll
    for (int ii = 0; ii < 4; ++ii) {
        int idx = ii * 256 + tid;
        float v = red[idx] + red[1024 + idx] + red[2048 + idx] + red[3072 + idx];
        int f = idx >> 8;
        int r = (idx >> 6) & 3, ln = idx & 63;
        int o = (f >> 1) * 16 + (ln >> 4) * 4 + r;   // D row = quad*4+reg
        int m = ln & 15;                              // D col = lane&15
        if (o < CC) atomicAdd(cPdst + (f & 1) * 320 + o * 16 + m, v);
    }
}

// ---------------- k_fc0_dft ----------------
__global__ __launch_bounds__(256, 4) void k_fc0_dft(const float* __restrict__ x,
        const float* __restrict__ pd, const float* __restrict__ w,
        const float* __restrict__ bias, const float* __restrict__ invmax,
        float* __restrict__ h, float* __restrict__ cP0) {
    __shared__ __align__(16) unsigned short sh_hA[32 * RP];
    __shared__ __align__(16) unsigned short sh_ph[32 * RP];
    __shared__ float lw[2 * CC], lb[CC];
    int tid = threadIdx.x;
    if (tid < 2 * CC) lw[tid] = w[tid];
    if (tid < CC) lb[tid] = bias[tid];
    {
        unsigned* z = (unsigned*)(sh_hA + CC * RP);
        for (int i = tid; i < (32 - CC) * RP / 2; i += 256) z[i] = 0;
    }
    __syncthreads();
    int b = blockIdx.y;
    int s = blockIdx.x * 256 + tid;
    float xv = x[(size_t)b * SS + s];
    float g  = pd[s] * invmax[0];
    float* hp = h + (size_t)b * CC * SS + s;
    float u = (float)s * (1.0f / 32768.0f);
    float s1, c1; sincospif(u, &s1, &c1);
    float cm = 1.0f, sm = 0.0f;
    #pragma unroll
    for (int m = 0; m < NM; ++m) {
        sh_ph[m * RP + tid]        = f2bf(cm);
        sh_ph[(16 + m) * RP + tid] = f2bf(sm);
        float cn = cm * c1 - sm * s1;
        sm = sm * c1 + cm * s1;
        cm = cn;
    }
    #pragma unroll
    for (int c = 0; c < CC; ++c) {
        float v = xv * lw[c] + g * lw[CC + c] + lb[c];
        hp[(size_t)c * SS] = v;
        sh_hA[c * RP + tid] = f2bf(v);
    }
    __syncthreads();
    dft_phase(sh_hA, sh_ph, tid, cP0 + ((size_t)(blockIdx.x & (NSLOT - 1)) * BB + b) * 640);
}

// ---------------- k_point_dft (layers 0..2: gelu + next-layer DFT) ----------
__global__ __launch_bounds__(256, 4) void k_point_dft(float* __restrict__ h,
        const float* __restrict__ ww, const float* __restrict__ wb,
        const float* __restrict__ cA, const float* __restrict__ cB,
        float* __restrict__ cPn) {
    __shared__ __align__(16) unsigned short sh_hA[32 * RP];
    __shared__ __align__(16) unsigned short sh_ph[32 * RP];
    __shared__ float lww[CC * CC], lwb[CC], lA[CC * NM], lB[CC * NM];
    int tid = threadIdx.x;
    int b = blockIdx.y;
    for (int i = tid; i < CC * CC; i += 256) lww[i] = ww[i];
    if (tid < CC) lwb[tid] = wb[tid];
    for (int i = tid; i < CC * NM; i += 256) { lA[i] = cA[b * CC * NM + i]; lB[i] = cB[b * CC * NM + i]; }
    {
        unsigned* z = (unsigned*)(sh_hA + CC * RP);
        for (int i = tid; i < (32 - CC) * RP / 2; i += 256) z[i] = 0;
    }
    __syncthreads();
    int s = blockIdx.x * 256 + tid;
    float* hp = h + (size_t)b * CC * SS + s;
    float u = (float)s * (1.0f / 32768.0f);
    float s1, c1; sincospif(u, &s1, &c1);
    float cm[NM], sm[NM];
    cm[0] = 1.0f; sm[0] = 0.0f;
    #pragma unroll
    for (int m = 1; m < NM; ++m) {
        cm[m] = cm[m - 1] * c1 - sm[m - 1] * s1;
        sm[m] = sm[m - 1] * c1 + cm[m - 1] * s1;
    }
    #pragma unroll
    for (int m = 0; m < NM; ++m) {
        sh_ph[m * RP + tid]        = f2bf(cm[m]);
        sh_ph[(16 + m) * RP + tid] = f2bf(sm[m]);
    }
    float hv[CC];
    #pragma unroll
    for (int c = 0; c < CC; ++c) hv[c] = hp[(size_t)c * SS];
    #pragma unroll 2
    for (int o = 0; o < CC; ++o) {
        float a = lwb[o];
        #pragma unroll
        for (int c = 0; c < CC; ++c) a += lww[o * CC + c] * hv[c];
        #pragma unroll
        for (int m = 0; m < NM; ++m)
            a += lA[o * NM + m] * cm[m] + lB[o * NM + m] * sm[m];
        a = gelu_fast(a);
        hp[(size_t)o * SS] = a;
        sh_hA[o * RP + tid] = f2bf(a);
    }
    __syncthreads();
    dft_phase(sh_hA, sh_ph, tid, cPn + ((size_t)(blockIdx.x & (NSLOT - 1)) * BB + b) * 640);
}

// ---------------- k_mix: 16-slot partial reduce + complex mixing ------------
__global__ __launch_bounds__(320) void k_mix(const float* __restrict__ cP,
                                             const float* __restrict__ wre, const float* __restrict__ wim,
                                             float* __restrict__ cA, float* __restrict__ cB) {
    int b = blockIdx.x, tid = threadIdx.x;
    __shared__ float PQ[640];
    const float* base = cP + (size_t)b * 640;
    int i = tid >> 4, m = tid & 15;
    float sP = 0.f, sQ = 0.f;
    #pragma unroll 4
    for (int sl = 0; sl < NSLOT; ++sl) {
        sP += base[(size_t)sl * BB * 640 + tid];
        sQ += base[(size_t)sl * BB * 640 + 320 + tid];
    }
    PQ[i * 32 + m]      = sP;
    PQ[i * 32 + 16 + m] = sQ;
    __syncthreads();
    int o = i;
    float reY = 0.f, imY = 0.f;
    #pragma unroll
    for (int c = 0; c < CC; ++c) {
        float P = PQ[c * 32 + m], Q = PQ[c * 32 + 16 + m];
        float wr = wre[(size_t)(c * CC + o) * NM + m];
        float wi = wim[(size_t)(c * CC + o) * NM + m];
        reY += P * wr + Q * wi;                // X = P - iQ
        imY += P * wi - Q * wr;
    }
    const float invS = 1.0f / (float)SS;
    float a, bb;
    if (m == 0) { a = reY * invS; bb = 0.0f; } // irfft drops Im(DC)
    else        { a = 2.0f * reY * invS; bb = -2.0f * imY * invS; }
    cA[(size_t)(b * CC + o) * NM + m] = a;
    cB[(size_t)(b * CC + o) * NM + m] = bb;
}

// ---------------- k_point_final: layer-3 point op + fc1 MFMA + gelu + fc2 ---
// (256,2): natural VGPR alloc (R8's (256,3) squeezed to 84 regs while the
// early-hoisted 64-reg B-fragment payload was live across the point-op ->
// 647 MB scratch spill). B-fragments now loaded AFTER the point-op; LDS
// 43.5 KB still allows 3 blocks/CU.
__global__ __launch_bounds__(256, 2) void k_point_final(const float* __restrict__ h,
        const float* __restrict__ ww, const float* __restrict__ wb,
        const float* __restrict__ cA, const float* __restrict__ cB,
        const unsigned short* __restrict__ w1Tg, const float* __restrict__ b1,
        const float* __restrict__ w2, const float* __restrict__ b2,
        float* __restrict__ out) {
    __shared__ __align__(16) unsigned short hT[256 * WP];   // 36.9 KB
    __shared__ float lww[CC * CC], lwb[CC], lA[CC * NM], lB[CC * NM];
    __shared__ float lb1[HH], lw2[HH], outS[256];
    int tid = threadIdx.x;
    int b = blockIdx.y;
    for (int i = tid; i < CC * CC; i += 256) lww[i] = ww[i];
    if (tid < CC) lwb[tid] = wb[tid];
    for (int i = tid; i < CC * NM; i += 256) { lA[i] = cA[b * CC * NM + i]; lB[i] = cB[b * CC * NM + i]; }
    if (tid < HH) { lb1[tid] = b1[tid]; lw2[tid] = w2[tid]; }
    __syncthreads();

    // point op (layer 3, no gelu), pack own hT row
    int s = blockIdx.x * 256 + tid;
    const float* hp = h + (size_t)b * CC * SS + s;
    float u = (float)s * (1.0f / 32768.0f);
    float s1, c1; sincospif(u, &s1, &c1);
    float cm[NM], sm[NM];
    cm[0] = 1.0f; sm[0] = 0.0f;
    #pragma unroll
    for (int m = 1; m < NM; ++m) {
        cm[m] = cm[m - 1] * c1 - sm[m - 1] * s1;
        sm[m] = sm[m - 1] * c1 + cm[m - 1] * s1;
    }
    float hv[CC];
    #pragma unroll
    for (int c = 0; c < CC; ++c) hv[c] = hp[(size_t)c * SS];
    short8 rowf[8];
    #pragma unroll
    for (int ch = 0; ch < 8; ++ch) rowf[ch] = (short8){0,0,0,0,0,0,0,0};
    #pragma unroll        // FULL unroll required (R5 scratch lesson)
    for (int o = 0; o < CC; ++o) {
        float a = lwb[o];
        #pragma unroll
        for (int c = 0; c < CC; ++c) a += lww[o * CC + c] * hv[c];
        #pragma unroll
        for (int m = 0; m < NM; ++m)
            a += lA[o * NM + m] * cm[m] + lB[o * NM + m] * sm[m];
        unsigned short hi = f2bf(a);
        rowf[o >> 3][o & 7]       = (short)hi;
        rowf[4 + (o >> 3)][o & 7] = (short)f2bf(a - bf2f(hi));
    }
    #pragma unroll
    for (int ch = 0; ch < 8; ++ch)
        *(short8*)(hT + tid * WP + ch * 8) = rowf[ch];
    __syncthreads();

    // fc1 B-fragments from global (L2-resident 16 KB) — loaded HERE, not
    // before the point-op (R8 spill lesson)
    int wave = tid >> 6, lane = tid & 63;
    int col = lane & 15, quad = lane >> 4;
    short8 bhi[8], blo[8];
    #pragma unroll
    for (int nt = 0; nt < 8; ++nt) {
        bhi[nt] = *(const short8*)(w1Tg + (size_t)(nt * 16 + col) * 64 + quad * 8);
        blo[nt] = *(const short8*)(w1Tg + (size_t)(nt * 16 + col) * 64 + 32 + quad * 8);
    }
    float lb1r[8], w2r[8];
    #pragma unroll
    for (int nt = 0; nt < 8; ++nt) { lb1r[nt] = lb1[nt * 16 + col]; w2r[nt] = lw2[nt * 16 + col]; }
    float b2v = b2[0];
    #pragma unroll
    for (int mt = 0; mt < 4; ++mt) {
        int srow = wave * 64 + mt * 16 + col;     // A row m = lane&15
        short8 ahi = *(const short8*)(hT + srow * WP + quad * 8);
        short8 alo = *(const short8*)(hT + srow * WP + 32 + quad * 8);
        float part[4] = {0.f, 0.f, 0.f, 0.f};
        #pragma unroll
        for (int nt = 0; nt < 8; ++nt) {
            floatx4 a = {0.f, 0.f, 0.f, 0.f};
            a = __builtin_amdgcn_mfma_f32_16x16x32_bf16(ahi, bhi[nt], a, 0, 0, 0);
            a = __builtin_amdgcn_mfma_f32_16x16x32_bf16(ahi, blo[nt], a, 0, 0, 0);
            a = __builtin_amdgcn_mfma_f32_16x16x32_bf16(alo, bhi[nt], a, 0, 0, 0);
            #pragma unroll
            for (int r = 0; r < 4; ++r) {
                float t = gelu_fast(a[r] + lb1r[nt]);
                part[r] += t * w2r[nt];
            }
        }
        #pragma unroll
        for (int r = 0; r < 4; ++r) {
            float p = part[r];
            p += __shfl_xor(p, 1, 64);
            p += __shfl_xor(p, 2, 64);
            p += __shfl_xor(p, 4, 64);
            p += __shfl_xor(p, 8, 64);
            if (col == 0) outS[wave * 64 + mt * 16 + quad * 4 + r] = p + b2v;
        }
    }
    __syncthreads();
    out[(size_t)b * SS + blockIdx.x * 256 + tid] = outS[tid];
}

extern "C" void kernel_launch(void* const* d_in, const int* in_sizes, int n_in,
                              void* d_out, int out_size, void* d_ws, size_t ws_size,
                              hipStream_t stream) {
    (void)in_sizes; (void)n_in; (void)out_size; (void)ws_size;
    const float* x    = (const float*)d_in[0];
    const float* pd   = (const float*)d_in[1];
    const float* fc0w = (const float*)d_in[2];
    const float* fc0b = (const float*)d_in[3];
    const float* fc1w = (const float*)d_in[4];
    const float* fc1b = (const float*)d_in[5];
    const float* fc2w = (const float*)d_in[6];
    const float* fc2b = (const float*)d_in[7];

    char* ws = (char*)d_ws;
    float* h = (float*)ws;
    size_t off = (size_t)BB * CC * SS * 4;                            // 167.8 MB
    float* cP = (float*)(ws + off); off += (size_t)4 * NSLOT * BB * 640 * 4;  // 5.24 MB
    float* cA = (float*)(ws + off); off += (size_t)BB * CC * NM * 4;
    float* cB = (float*)(ws + off); off += (size_t)BB * CC * NM * 4;
    float* invmax = (float*)(ws + off); off += 256;
    unsigned short* w1Tg = (unsigned short*)(ws + off); off += (size_t)HH * 64 * 2;  // 16 KB
    const size_t CPL = (size_t)NSLOT * BB * 640;   // floats per layer-slot set

    dim3 gBS(SS / 256, BB);

    k_prep<<<1282, 256, 0, stream>>>(pd, fc1w, invmax, cP, w1Tg);
    k_fc0_dft<<<gBS, 256, 0, stream>>>(x, pd, fc0w, fc0b, invmax, h, cP);

    for (int l = 0; l < 3; ++l) {
        const float* wre = (const float*)d_in[8 + 4 * l];
        const float* wim = (const float*)d_in[9 + 4 * l];
        const float* ww  = (const float*)d_in[10 + 4 * l];
        const float* wb  = (const float*)d_in[11 + 4 * l];
        k_mix<<<BB, 320, 0, stream>>>(cP + (size_t)l * CPL, wre, wim, cA, cB);
        k_point_dft<<<gBS, 256, 0, stream>>>(h, ww, wb, cA, cB,
                                             cP + (size_t)(l + 1) * CPL);
    }
    {   // layer 3 fused with fc1/gelu/fc2
        const float* wre = (const float*)d_in[20];
        const float* wim = (const float*)d_in[21];
        const float* ww  = (const float*)d_in[22];
        const float* wb  = (const float*)d_in[23];
        k_mix<<<BB, 320, 0, stream>>>(cP + (size_t)3 * CPL, wre, wim, cA, cB);
        k_point_final<<<gBS, 256, 0, stream>>>(h, ww, wb, cA, cB,
                                               w1Tg, fc1b, fc2w, fc2b, (float*)d_out);
    }
}

// Round 10
// 824.430 us; speedup vs baseline: 1.5558x; 1.1455x over previous
//
#include <hip/hip_runtime.h>
#include <math.h>

#define BB 32
#define SS 65536
#define CC 20
#define NM 16
#define HH 128
#define RP 264   // DFT LDS row pitch (bf16 elems)
#define WP 72    // hT row pitch (bf16 elems): 36 dwords; b128-aligned rows
#define NSLOT 16

using short8  = __attribute__((ext_vector_type(8))) short;
using floatx4 = __attribute__((ext_vector_type(4))) float;

__device__ __forceinline__ unsigned short f2bf(float f) {
    union { float f; unsigned u; } v; v.f = f;
    unsigned u = v.u;
    return (unsigned short)((u + 0x7FFFu + ((u >> 16) & 1u)) >> 16);   // RNE
}
__device__ __forceinline__ float bf2f(unsigned short h) {
    union { unsigned u; float f; } v; v.u = ((unsigned)h) << 16; return v.f;
}
__device__ __forceinline__ unsigned short f2bflo(float a) {
    return f2bf(a - bf2f(f2bf(a)));
}

// Branchless gelu: erf via Abramowitz-Stegun 7.1.26 (abs err <= 1.5e-7)
__device__ __forceinline__ float gelu_fast(float v) {
    float z = fabsf(v) * 0.7071067811865476f;
    float t = __builtin_amdgcn_rcpf(1.0f + 0.3275911f * z);
    float poly = t * (0.254829592f + t * (-0.284496736f +
                 t * (1.421413741f + t * (-1.453152027f + t * 1.061405429f))));
    float e = __expf(-z * z);
    float erfz = 1.0f - poly * e;
    float se = copysignf(erfz, v);
    return 0.5f * v * (1.0f + se);
}

// ---------------- k_prep: max-reduce + zero cP + build w1T(global) ----------
__global__ __launch_bounds__(256) void k_prep(const float* __restrict__ pd,
                                              const float* __restrict__ w1,
                                              float* __restrict__ invmax,
                                              float* __restrict__ cP,
                                              unsigned short* __restrict__ w1Tg) {
    int bx = blockIdx.x;
    if (bx == 0) {
        __shared__ float red[256];
        int t = threadIdx.x;
        float m = -1e30f;
        for (int i = t; i < SS; i += 256) m = fmaxf(m, pd[i]);
        red[t] = m; __syncthreads();
        for (int off = 128; off > 0; off >>= 1) {
            if (t < off) red[t] = fmaxf(red[t], red[t + off]);
            __syncthreads();
        }
        if (t == 0) invmax[0] = 1.0f / red[0];
    } else if (bx <= 1280) {
        int idx = (bx - 1) * 256 + threadIdx.x;   // 1280*256 float4 = 4*16*32*640 floats
        float4 z = {0.f, 0.f, 0.f, 0.f};
        ((float4*)cP)[idx] = z;
    } else {
        for (int idx = threadIdx.x; idx < HH * 64; idx += 256) {
            int j = idx >> 6, k = idx & 63;
            unsigned short r = 0;
            if (k < CC) r = f2bf(w1[k * HH + j]);
            else if (k >= 32 && k < 32 + CC) r = f2bflo(w1[(k - 32) * HH + j]);
            w1Tg[idx] = r;
        }
    }
}

// ---------------- shared DFT tail: LDS-staged MFMA partial DFT --------------
__device__ __forceinline__ void dft_phase(unsigned short* sh_hA, unsigned short* sh_ph,
                                          int tid, float* cPdst) {
    int wave = tid >> 6, lane = tid & 63;
    int quad = lane >> 4, frow = lane & 15;
    floatx4 acc00 = {0.f,0.f,0.f,0.f}, acc01 = {0.f,0.f,0.f,0.f};
    floatx4 acc10 = {0.f,0.f,0.f,0.f}, acc11 = {0.f,0.f,0.f,0.f};
    int kb = wave * 64 + quad * 8;
    #pragma unroll
    for (int kc = 0; kc < 2; ++kc) {
        int k = kb + kc * 32;
        short8 a0 = *(const short8*)(sh_hA + frow * RP + k);
        short8 a1 = *(const short8*)(sh_hA + (16 + frow) * RP + k);
        short8 bc = *(const short8*)(sh_ph + frow * RP + k);
        short8 bs = *(const short8*)(sh_ph + (16 + frow) * RP + k);
        acc00 = __builtin_amdgcn_mfma_f32_16x16x32_bf16(a0, bc, acc00, 0, 0, 0);
        acc01 = __builtin_amdgcn_mfma_f32_16x16x32_bf16(a0, bs, acc01, 0, 0, 0);
        acc10 = __builtin_amdgcn_mfma_f32_16x16x32_bf16(a1, bc, acc10, 0, 0, 0);
        acc11 = __builtin_amdgcn_mfma_f32_16x16x32_bf16(a1, bs, acc11, 0, 0, 0);
    }
    __syncthreads();
    float* red = (float*)sh_hA;
    #pragma unroll
    for (int r = 0; r < 4; ++r) {
        red[wave * 1024 + 0 * 256 + r * 64 + lane] = acc00[r];
        red[wave * 1024 + 1 * 256 + r * 64 + lane] = acc01[r];
        red[wave * 1024 + 2 * 256 + r * 64 + lane] = acc10[r];
        red[wave * 1024 + 3 * 256 + r * 64 + lane] = acc11[r];
    }
    __syncthreads();
    #pragma unroll
    for (int ii = 0; ii < 4; ++ii) {
        int idx = ii * 256 + tid;
        float v = red[idx] + red[1024 + idx] + red[2048 + idx] + red[3072 + idx];
        int f = idx >> 8;
        int r = (idx >> 6) & 3, ln = idx & 63;
        int o = (f >> 1) * 16 + (ln >> 4) * 4 + r;   // D row = quad*4+reg
        int m = ln & 15;                              // D col = lane&15
        if (o < CC) atomicAdd(cPdst + (f & 1) * 320 + o * 16 + m, v);
    }
}

// ---------------- k_fc0_dft ----------------
// Weights read directly from global with uniform indices -> scalar loads
// (SGPR operands), no LDS weight staging.
__global__ __launch_bounds__(256, 4) void k_fc0_dft(const float* __restrict__ x,
        const float* __restrict__ pd, const float* __restrict__ w,
        const float* __restrict__ bias, const float* __restrict__ invmax,
        float* __restrict__ h, float* __restrict__ cP0) {
    __shared__ __align__(16) unsigned short sh_hA[32 * RP];
    __shared__ __align__(16) unsigned short sh_ph[32 * RP];
    int tid = threadIdx.x;
    {
        unsigned* z = (unsigned*)(sh_hA + CC * RP);
        for (int i = tid; i < (32 - CC) * RP / 2; i += 256) z[i] = 0;
    }
    int b = blockIdx.y;
    int s = blockIdx.x * 256 + tid;
    float xv = x[(size_t)b * SS + s];
    float g  = pd[s] * invmax[0];
    float* hp = h + (size_t)b * CC * SS + s;
    float u = (float)s * (1.0f / 32768.0f);
    float s1, c1; sincospif(u, &s1, &c1);
    float cm = 1.0f, sm = 0.0f;
    #pragma unroll
    for (int m = 0; m < NM; ++m) {
        sh_ph[m * RP + tid]        = f2bf(cm);
        sh_ph[(16 + m) * RP + tid] = f2bf(sm);
        float cn = cm * c1 - sm * s1;
        sm = sm * c1 + cm * s1;
        cm = cn;
    }
    #pragma unroll
    for (int c = 0; c < CC; ++c) {
        float v = xv * w[c] + g * w[CC + c] + bias[c];
        hp[(size_t)c * SS] = v;
        sh_hA[c * RP + tid] = f2bf(v);
    }
    __syncthreads();
    dft_phase(sh_hA, sh_ph, tid, cP0 + ((size_t)(blockIdx.x & (NSLOT - 1)) * BB + b) * 640);
}

// ---------------- k_point_dft (layers 0..2: gelu + next-layer DFT) ----------
// Point-op weights via direct global uniform reads (s_load -> SGPR operand
// FMA) — removes ~1040 ds_read_b32/thread (R9: VALU/LDS issue-bound at 64%).
__global__ __launch_bounds__(256, 4) void k_point_dft(float* __restrict__ h,
        const float* __restrict__ ww, const float* __restrict__ wb,
        const float* __restrict__ cA, const float* __restrict__ cB,
        float* __restrict__ cPn) {
    __shared__ __align__(16) unsigned short sh_hA[32 * RP];
    __shared__ __align__(16) unsigned short sh_ph[32 * RP];
    int tid = threadIdx.x;
    int b = blockIdx.y;
    {
        unsigned* z = (unsigned*)(sh_hA + CC * RP);
        for (int i = tid; i < (32 - CC) * RP / 2; i += 256) z[i] = 0;
    }
    const float* wA = cA + (size_t)b * CC * NM;
    const float* wB = cB + (size_t)b * CC * NM;
    int s = blockIdx.x * 256 + tid;
    float* hp = h + (size_t)b * CC * SS + s;
    float u = (float)s * (1.0f / 32768.0f);
    float s1, c1; sincospif(u, &s1, &c1);
    float cm[NM], sm[NM];
    cm[0] = 1.0f; sm[0] = 0.0f;
    #pragma unroll
    for (int m = 1; m < NM; ++m) {
        cm[m] = cm[m - 1] * c1 - sm[m - 1] * s1;
        sm[m] = sm[m - 1] * c1 + cm[m - 1] * s1;
    }
    #pragma unroll
    for (int m = 0; m < NM; ++m) {
        sh_ph[m * RP + tid]        = f2bf(cm[m]);
        sh_ph[(16 + m) * RP + tid] = f2bf(sm[m]);
    }
    float hv[CC];
    #pragma unroll
    for (int c = 0; c < CC; ++c) hv[c] = hp[(size_t)c * SS];
    #pragma unroll 2
    for (int o = 0; o < CC; ++o) {
        float a = wb[o];
        #pragma unroll
        for (int c = 0; c < CC; ++c) a += ww[o * CC + c] * hv[c];
        #pragma unroll
        for (int m = 0; m < NM; ++m)
            a += wA[o * NM + m] * cm[m] + wB[o * NM + m] * sm[m];
        a = gelu_fast(a);
        hp[(size_t)o * SS] = a;
        sh_hA[o * RP + tid] = f2bf(a);
    }
    __syncthreads();
    dft_phase(sh_hA, sh_ph, tid, cPn + ((size_t)(blockIdx.x & (NSLOT - 1)) * BB + b) * 640);
}

// ---------------- k_mix: 16-slot partial reduce + complex mixing ------------
__global__ __launch_bounds__(320) void k_mix(const float* __restrict__ cP,
                                             const float* __restrict__ wre, const float* __restrict__ wim,
                                             float* __restrict__ cA, float* __restrict__ cB) {
    int b = blockIdx.x, tid = threadIdx.x;
    __shared__ float PQ[640];
    const float* base = cP + (size_t)b * 640;
    int i = tid >> 4, m = tid & 15;
    float sP = 0.f, sQ = 0.f;
    #pragma unroll 4
    for (int sl = 0; sl < NSLOT; ++sl) {
        sP += base[(size_t)sl * BB * 640 + tid];
        sQ += base[(size_t)sl * BB * 640 + 320 + tid];
    }
    PQ[i * 32 + m]      = sP;
    PQ[i * 32 + 16 + m] = sQ;
    __syncthreads();
    int o = i;
    float reY = 0.f, imY = 0.f;
    #pragma unroll
    for (int c = 0; c < CC; ++c) {
        float P = PQ[c * 32 + m], Q = PQ[c * 32 + 16 + m];
        float wr = wre[(size_t)(c * CC + o) * NM + m];
        float wi = wim[(size_t)(c * CC + o) * NM + m];
        reY += P * wr + Q * wi;                // X = P - iQ
        imY += P * wi - Q * wr;
    }
    const float invS = 1.0f / (float)SS;
    float a, bb;
    if (m == 0) { a = reY * invS; bb = 0.0f; } // irfft drops Im(DC)
    else        { a = 2.0f * reY * invS; bb = -2.0f * imY * invS; }
    cA[(size_t)(b * CC + o) * NM + m] = a;
    cB[(size_t)(b * CC + o) * NM + m] = bb;
}

// ---------------- k_point_final: layer-3 point op + fc1 MFMA + gelu + fc2 ---
// Weights via uniform global reads (s_load); b1/w2 via lane-indexed L2 reads.
// LDS: hT + outS only (~38 KB) -> 4 blocks/CU. B-fragments loaded after the
// point-op (R8 spill lesson). Full o-unroll (R5 scratch lesson).
__global__ __launch_bounds__(256, 2) void k_point_final(const float* __restrict__ h,
        const float* __restrict__ ww, const float* __restrict__ wb,
        const float* __restrict__ cA, const float* __restrict__ cB,
        const unsigned short* __restrict__ w1Tg, const float* __restrict__ b1,
        const float* __restrict__ w2, const float* __restrict__ b2,
        float* __restrict__ out) {
    __shared__ __align__(16) unsigned short hT[256 * WP];   // 36.9 KB
    __shared__ float outS[256];
    int tid = threadIdx.x;
    int b = blockIdx.y;
    const float* wA = cA + (size_t)b * CC * NM;
    const float* wB = cB + (size_t)b * CC * NM;

    // point op (layer 3, no gelu), pack own hT row
    int s = blockIdx.x * 256 + tid;
    const float* hp = h + (size_t)b * CC * SS + s;
    float u = (float)s * (1.0f / 32768.0f);
    float s1, c1; sincospif(u, &s1, &c1);
    float cm[NM], sm[NM];
    cm[0] = 1.0f; sm[0] = 0.0f;
    #pragma unroll
    for (int m = 1; m < NM; ++m) {
        cm[m] = cm[m - 1] * c1 - sm[m - 1] * s1;
        sm[m] = sm[m - 1] * c1 + cm[m - 1] * s1;
    }
    float hv[CC];
    #pragma unroll
    for (int c = 0; c < CC; ++c) hv[c] = hp[(size_t)c * SS];
    short8 rowf[8];
    #pragma unroll
    for (int ch = 0; ch < 8; ++ch) rowf[ch] = (short8){0,0,0,0,0,0,0,0};
    #pragma unroll        // FULL unroll required (R5 scratch lesson)
    for (int o = 0; o < CC; ++o) {
        float a = wb[o];
        #pragma unroll
        for (int c = 0; c < CC; ++c) a += ww[o * CC + c] * hv[c];
        #pragma unroll
        for (int m = 0; m < NM; ++m)
            a += wA[o * NM + m] * cm[m] + wB[o * NM + m] * sm[m];
        unsigned short hi = f2bf(a);
        rowf[o >> 3][o & 7]       = (short)hi;
        rowf[4 + (o >> 3)][o & 7] = (short)f2bf(a - bf2f(hi));
    }
    #pragma unroll
    for (int ch = 0; ch < 8; ++ch)
        *(short8*)(hT + tid * WP + ch * 8) = rowf[ch];
    __syncthreads();

    // fc1 B-fragments from global (L2-resident 16 KB) — loaded here, not
    // before the point-op (R8 spill lesson)
    int wave = tid >> 6, lane = tid & 63;
    int col = lane & 15, quad = lane >> 4;
    short8 bhi[8], blo[8];
    #pragma unroll
    for (int nt = 0; nt < 8; ++nt) {
        bhi[nt] = *(const short8*)(w1Tg + (size_t)(nt * 16 + col) * 64 + quad * 8);
        blo[nt] = *(const short8*)(w1Tg + (size_t)(nt * 16 + col) * 64 + 32 + quad * 8);
    }
    float lb1r[8], w2r[8];
    #pragma unroll
    for (int nt = 0; nt < 8; ++nt) { lb1r[nt] = b1[nt * 16 + col]; w2r[nt] = w2[nt * 16 + col]; }
    float b2v = b2[0];
    #pragma unroll
    for (int mt = 0; mt < 4; ++mt) {
        int srow = wave * 64 + mt * 16 + col;     // A row m = lane&15
        short8 ahi = *(const short8*)(hT + srow * WP + quad * 8);
        short8 alo = *(const short8*)(hT + srow * WP + 32 + quad * 8);
        float part[4] = {0.f, 0.f, 0.f, 0.f};
        #pragma unroll
        for (int nt = 0; nt < 8; ++nt) {
            floatx4 a = {0.f, 0.f, 0.f, 0.f};
            a = __builtin_amdgcn_mfma_f32_16x16x32_bf16(ahi, bhi[nt], a, 0, 0, 0);
            a = __builtin_amdgcn_mfma_f32_16x16x32_bf16(ahi, blo[nt], a, 0, 0, 0);
            a = __builtin_amdgcn_mfma_f32_16x16x32_bf16(alo, bhi[nt], a, 0, 0, 0);
            #pragma unroll
            for (int r = 0; r < 4; ++r) {
                float t = gelu_fast(a[r] + lb1r[nt]);
                part[r] += t * w2r[nt];
            }
        }
        #pragma unroll
        for (int r = 0; r < 4; ++r) {
            float p = part[r];
            p += __shfl_xor(p, 1, 64);
            p += __shfl_xor(p, 2, 64);
            p += __shfl_xor(p, 4, 64);
            p += __shfl_xor(p, 8, 64);
            if (col == 0) outS[wave * 64 + mt * 16 + quad * 4 + r] = p + b2v;
        }
    }
    __syncthreads();
    out[(size_t)b * SS + blockIdx.x * 256 + tid] = outS[tid];
}

extern "C" void kernel_launch(void* const* d_in, const int* in_sizes, int n_in,
                              void* d_out, int out_size, void* d_ws, size_t ws_size,
                              hipStream_t stream) {
    (void)in_sizes; (void)n_in; (void)out_size; (void)ws_size;
    const float* x    = (const float*)d_in[0];
    const float* pd   = (const float*)d_in[1];
    const float* fc0w = (const float*)d_in[2];
    const float* fc0b = (const float*)d_in[3];
    const float* fc1w = (const float*)d_in[4];
    const float* fc1b = (const float*)d_in[5];
    const float* fc2w = (const float*)d_in[6];
    const float* fc2b = (const float*)d_in[7];

    char* ws = (char*)d_ws;
    float* h = (float*)ws;
    size_t off = (size_t)BB * CC * SS * 4;                            // 167.8 MB
    float* cP = (float*)(ws + off); off += (size_t)4 * NSLOT * BB * 640 * 4;  // 5.24 MB
    float* cA = (float*)(ws + off); off += (size_t)BB * CC * NM * 4;
    float* cB = (float*)(ws + off); off += (size_t)BB * CC * NM * 4;
    float* invmax = (float*)(ws + off); off += 256;
    unsigned short* w1Tg = (unsigned short*)(ws + off); off += (size_t)HH * 64 * 2;  // 16 KB
    const size_t CPL = (size_t)NSLOT * BB * 640;   // floats per layer-slot set

    dim3 gBS(SS / 256, BB);

    k_prep<<<1282, 256, 0, stream>>>(pd, fc1w, invmax, cP, w1Tg);
    k_fc0_dft<<<gBS, 256, 0, stream>>>(x, pd, fc0w, fc0b, invmax, h, cP);

    for (int l = 0; l < 3; ++l) {
        const float* wre = (const float*)d_in[8 + 4 * l];
        const float* wim = (const float*)d_in[9 + 4 * l];
        const float* ww  = (const float*)d_in[10 + 4 * l];
        const float* wb  = (const float*)d_in[11 + 4 * l];
        k_mix<<<BB, 320, 0, stream>>>(cP + (size_t)l * CPL, wre, wim, cA, cB);
        k_point_dft<<<gBS, 256, 0, stream>>>(h, ww, wb, cA, cB,
                                             cP + (size_t)(l + 1) * CPL);
    }
    {   // layer 3 fused with fc1/gelu/fc2
        const float* wre = (const float*)d_in[20];
        const float* wim = (const float*)d_in[21];
        const float* ww  = (const float*)d_in[22];
        const float* wb  = (const float*)d_in[23];
        k_mix<<<BB, 320, 0, stream>>>(cP + (size_t)3 * CPL, wre, wim, cA, cB);
        k_point_final<<<gBS, 256, 0, stream>>>(h, ww, wb, cA, cB,
                                               w1Tg, fc1b, fc2w, fc2b, (float*)d_out);
    }
}

// Round 11
// 779.004 us; speedup vs baseline: 1.6466x; 1.0583x over previous
//
#include <hip/hip_runtime.h>
#include <math.h>

#define BB 32
#define SS 65536
#define CC 20
#define NM 16
#define HH 128
#define RP 264   // DFT LDS row pitch (bf16 elems)
#define WP 72    // hT row pitch (bf16 elems): 36 dwords; b128-aligned rows
#define NSLOT 16

using short8  = __attribute__((ext_vector_type(8))) short;
using floatx4 = __attribute__((ext_vector_type(4))) float;

__device__ __forceinline__ unsigned short f2bf(float f) {
    union { float f; unsigned u; } v; v.f = f;
    unsigned u = v.u;
    return (unsigned short)((u + 0x7FFFu + ((u >> 16) & 1u)) >> 16);   // RNE
}
__device__ __forceinline__ float bf2f(unsigned short h) {
    union { unsigned u; float f; } v; v.u = ((unsigned)h) << 16; return v.f;
}
__device__ __forceinline__ unsigned short f2bflo(float a) {
    return f2bf(a - bf2f(f2bf(a)));
}

// Tanh-form gelu, native exp2/rcp: 6 regular VALU + 2 trans (~28 issue-cyc
// vs 44 for the A&S-erf version — R10 showed k_point_final == gelu issue).
// g = v - v*rcp(exp2(2*log2e*inner)+1), inner = sqrt(2/pi)*(v+0.044715 v^3).
// Saturates correctly at both ends (e->inf => g=v; e->0 => g=0).
// Max |delta vs exact erf-gelu| ~3e-4.
__device__ __forceinline__ float gelu_fast(float v) {
    float u = v * v;
    float inner = v * fmaf(0.0356774081f, u, 0.7978845608f);
    float e = __builtin_amdgcn_exp2f(inner * 2.8853900818f);
    float r = __builtin_amdgcn_rcpf(e + 1.0f);
    return fmaf(-v, r, v);
}

// ---------------- k_prep: max-reduce + zero cP + build w1T(global) ----------
__global__ __launch_bounds__(256) void k_prep(const float* __restrict__ pd,
                                              const float* __restrict__ w1,
                                              float* __restrict__ invmax,
                                              float* __restrict__ cP,
                                              unsigned short* __restrict__ w1Tg) {
    int bx = blockIdx.x;
    if (bx == 0) {
        __shared__ float red[256];
        int t = threadIdx.x;
        float m = -1e30f;
        for (int i = t; i < SS; i += 256) m = fmaxf(m, pd[i]);
        red[t] = m; __syncthreads();
        for (int off = 128; off > 0; off >>= 1) {
            if (t < off) red[t] = fmaxf(red[t], red[t + off]);
            __syncthreads();
        }
        if (t == 0) invmax[0] = 1.0f / red[0];
    } else if (bx <= 1280) {
        int idx = (bx - 1) * 256 + threadIdx.x;   // 1280*256 float4 = 4*16*32*640 floats
        float4 z = {0.f, 0.f, 0.f, 0.f};
        ((float4*)cP)[idx] = z;
    } else {
        for (int idx = threadIdx.x; idx < HH * 64; idx += 256) {
            int j = idx >> 6, k = idx & 63;
            unsigned short r = 0;
            if (k < CC) r = f2bf(w1[k * HH + j]);
            else if (k >= 32 && k < 32 + CC) r = f2bflo(w1[(k - 32) * HH + j]);
            w1Tg[idx] = r;
        }
    }
}

// ---------------- shared DFT tail: LDS-staged MFMA partial DFT --------------
__device__ __forceinline__ void dft_phase(unsigned short* sh_hA, unsigned short* sh_ph,
                                          int tid, float* cPdst) {
    int wave = tid >> 6, lane = tid & 63;
    int quad = lane >> 4, frow = lane & 15;
    floatx4 acc00 = {0.f,0.f,0.f,0.f}, acc01 = {0.f,0.f,0.f,0.f};
    floatx4 acc10 = {0.f,0.f,0.f,0.f}, acc11 = {0.f,0.f,0.f,0.f};
    int kb = wave * 64 + quad * 8;
    #pragma unroll
    for (int kc = 0; kc < 2; ++kc) {
        int k = kb + kc * 32;
        short8 a0 = *(const short8*)(sh_hA + frow * RP + k);
        short8 a1 = *(const short8*)(sh_hA + (16 + frow) * RP + k);
        short8 bc = *(const short8*)(sh_ph + frow * RP + k);
        short8 bs = *(const short8*)(sh_ph + (16 + frow) * RP + k);
        acc00 = __builtin_amdgcn_mfma_f32_16x16x32_bf16(a0, bc, acc00, 0, 0, 0);
        acc01 = __builtin_amdgcn_mfma_f32_16x16x32_bf16(a0, bs, acc01, 0, 0, 0);
        acc10 = __builtin_amdgcn_mfma_f32_16x16x32_bf16(a1, bc, acc10, 0, 0, 0);
        acc11 = __builtin_amdgcn_mfma_f32_16x16x32_bf16(a1, bs, acc11, 0, 0, 0);
    }
    __syncthreads();
    float* red = (float*)sh_hA;
    #pragma unroll
    for (int r = 0; r < 4; ++r) {
        red[wave * 1024 + 0 * 256 + r * 64 + lane] = acc00[r];
        red[wave * 1024 + 1 * 256 + r * 64 + lane] = acc01[r];
        red[wave * 1024 + 2 * 256 + r * 64 + lane] = acc10[r];
        red[wave * 1024 + 3 * 256 + r * 64 + lane] = acc11[r];
    }
    __syncthreads();
    #pragma unroll
    for (int ii = 0; ii < 4; ++ii) {
        int idx = ii * 256 + tid;
        float v = red[idx] + red[1024 + idx] + red[2048 + idx] + red[3072 + idx];
        int f = idx >> 8;
        int r = (idx >> 6) & 3, ln = idx & 63;
        int o = (f >> 1) * 16 + (ln >> 4) * 4 + r;   // D row = quad*4+reg
        int m = ln & 15;                              // D col = lane&15
        if (o < CC) atomicAdd(cPdst + (f & 1) * 320 + o * 16 + m, v);
    }
}

// ---------------- k_fc0_dft ----------------
__global__ __launch_bounds__(256, 4) void k_fc0_dft(const float* __restrict__ x,
        const float* __restrict__ pd, const float* __restrict__ w,
        const float* __restrict__ bias, const float* __restrict__ invmax,
        float* __restrict__ h, float* __restrict__ cP0) {
    __shared__ __align__(16) unsigned short sh_hA[32 * RP];
    __shared__ __align__(16) unsigned short sh_ph[32 * RP];
    int tid = threadIdx.x;
    {
        unsigned* z = (unsigned*)(sh_hA + CC * RP);
        for (int i = tid; i < (32 - CC) * RP / 2; i += 256) z[i] = 0;
    }
    int b = blockIdx.y;
    int s = blockIdx.x * 256 + tid;
    float xv = x[(size_t)b * SS + s];
    float g  = pd[s] * invmax[0];
    float* hp = h + (size_t)b * CC * SS + s;
    float u = (float)s * (1.0f / 32768.0f);
    float s1, c1; sincospif(u, &s1, &c1);
    float cm = 1.0f, sm = 0.0f;
    #pragma unroll
    for (int m = 0; m < NM; ++m) {
        sh_ph[m * RP + tid]        = f2bf(cm);
        sh_ph[(16 + m) * RP + tid] = f2bf(sm);
        float cn = cm * c1 - sm * s1;
        sm = sm * c1 + cm * s1;
        cm = cn;
    }
    #pragma unroll
    for (int c = 0; c < CC; ++c) {
        float v = xv * w[c] + g * w[CC + c] + bias[c];
        hp[(size_t)c * SS] = v;
        sh_hA[c * RP + tid] = f2bf(v);
    }
    __syncthreads();
    dft_phase(sh_hA, sh_ph, tid, cP0 + ((size_t)(blockIdx.x & (NSLOT - 1)) * BB + b) * 640);
}

// ---------------- k_point_dft (layers 0..2: gelu + next-layer DFT) ----------
__global__ __launch_bounds__(256, 4) void k_point_dft(float* __restrict__ h,
        const float* __restrict__ ww, const float* __restrict__ wb,
        const float* __restrict__ cA, const float* __restrict__ cB,
        float* __restrict__ cPn) {
    __shared__ __align__(16) unsigned short sh_hA[32 * RP];
    __shared__ __align__(16) unsigned short sh_ph[32 * RP];
    int tid = threadIdx.x;
    int b = blockIdx.y;
    {
        unsigned* z = (unsigned*)(sh_hA + CC * RP);
        for (int i = tid; i < (32 - CC) * RP / 2; i += 256) z[i] = 0;
    }
    const float* wA = cA + (size_t)b * CC * NM;
    const float* wB = cB + (size_t)b * CC * NM;
    int s = blockIdx.x * 256 + tid;
    float* hp = h + (size_t)b * CC * SS + s;
    float u = (float)s * (1.0f / 32768.0f);
    float s1, c1; sincospif(u, &s1, &c1);
    float cm[NM], sm[NM];
    cm[0] = 1.0f; sm[0] = 0.0f;
    #pragma unroll
    for (int m = 1; m < NM; ++m) {
        cm[m] = cm[m - 1] * c1 - sm[m - 1] * s1;
        sm[m] = sm[m - 1] * c1 + cm[m - 1] * s1;
    }
    #pragma unroll
    for (int m = 0; m < NM; ++m) {
        sh_ph[m * RP + tid]        = f2bf(cm[m]);
        sh_ph[(16 + m) * RP + tid] = f2bf(sm[m]);
    }
    float hv[CC];
    #pragma unroll
    for (int c = 0; c < CC; ++c) hv[c] = hp[(size_t)c * SS];
    #pragma unroll 2
    for (int o = 0; o < CC; ++o) {
        float a = wb[o];
        #pragma unroll
        for (int c = 0; c < CC; ++c) a += ww[o * CC + c] * hv[c];
        #pragma unroll
        for (int m = 0; m < NM; ++m)
            a += wA[o * NM + m] * cm[m] + wB[o * NM + m] * sm[m];
        a = gelu_fast(a);
        hp[(size_t)o * SS] = a;
        sh_hA[o * RP + tid] = f2bf(a);
    }
    __syncthreads();
    dft_phase(sh_hA, sh_ph, tid, cPn + ((size_t)(blockIdx.x & (NSLOT - 1)) * BB + b) * 640);
}

// ---------------- k_mix: 16-slot partial reduce + complex mixing ------------
__global__ __launch_bounds__(320) void k_mix(const float* __restrict__ cP,
                                             const float* __restrict__ wre, const float* __restrict__ wim,
                                             float* __restrict__ cA, float* __restrict__ cB) {
    int b = blockIdx.x, tid = threadIdx.x;
    __shared__ float PQ[640];
    const float* base = cP + (size_t)b * 640;
    int i = tid >> 4, m = tid & 15;
    float sP = 0.f, sQ = 0.f;
    #pragma unroll 4
    for (int sl = 0; sl < NSLOT; ++sl) {
        sP += base[(size_t)sl * BB * 640 + tid];
        sQ += base[(size_t)sl * BB * 640 + 320 + tid];
    }
    PQ[i * 32 + m]      = sP;
    PQ[i * 32 + 16 + m] = sQ;
    __syncthreads();
    int o = i;
    float reY = 0.f, imY = 0.f;
    #pragma unroll
    for (int c = 0; c < CC; ++c) {
        float P = PQ[c * 32 + m], Q = PQ[c * 32 + 16 + m];
        float wr = wre[(size_t)(c * CC + o) * NM + m];
        float wi = wim[(size_t)(c * CC + o) * NM + m];
        reY += P * wr + Q * wi;                // X = P - iQ
        imY += P * wi - Q * wr;
    }
    const float invS = 1.0f / (float)SS;
    float a, bb;
    if (m == 0) { a = reY * invS; bb = 0.0f; } // irfft drops Im(DC)
    else        { a = 2.0f * reY * invS; bb = -2.0f * imY * invS; }
    cA[(size_t)(b * CC + o) * NM + m] = a;
    cB[(size_t)(b * CC + o) * NM + m] = bb;
}

// ---------------- k_point_final: layer-3 point op + fc1 MFMA + gelu + fc2 ---
__global__ __launch_bounds__(256, 2) void k_point_final(const float* __restrict__ h,
        const float* __restrict__ ww, const float* __restrict__ wb,
        const float* __restrict__ cA, const float* __restrict__ cB,
        const unsigned short* __restrict__ w1Tg, const float* __restrict__ b1,
        const float* __restrict__ w2, const float* __restrict__ b2,
        float* __restrict__ out) {
    __shared__ __align__(16) unsigned short hT[256 * WP];   // 36.9 KB
    __shared__ float outS[256];
    int tid = threadIdx.x;
    int b = blockIdx.y;
    const float* wA = cA + (size_t)b * CC * NM;
    const float* wB = cB + (size_t)b * CC * NM;

    // point op (layer 3, no gelu), pack own hT row
    int s = blockIdx.x * 256 + tid;
    const float* hp = h + (size_t)b * CC * SS + s;
    float u = (float)s * (1.0f / 32768.0f);
    float s1, c1; sincospif(u, &s1, &c1);
    float cm[NM], sm[NM];
    cm[0] = 1.0f; sm[0] = 0.0f;
    #pragma unroll
    for (int m = 1; m < NM; ++m) {
        cm[m] = cm[m - 1] * c1 - sm[m - 1] * s1;
        sm[m] = sm[m - 1] * c1 + cm[m - 1] * s1;
    }
    float hv[CC];
    #pragma unroll
    for (int c = 0; c < CC; ++c) hv[c] = hp[(size_t)c * SS];
    short8 rowf[8];
    #pragma unroll
    for (int ch = 0; ch < 8; ++ch) rowf[ch] = (short8){0,0,0,0,0,0,0,0};
    #pragma unroll        // FULL unroll required (R5 scratch lesson)
    for (int o = 0; o < CC; ++o) {
        float a = wb[o];
        #pragma unroll
        for (int c = 0; c < CC; ++c) a += ww[o * CC + c] * hv[c];
        #pragma unroll
        for (int m = 0; m < NM; ++m)
            a += wA[o * NM + m] * cm[m] + wB[o * NM + m] * sm[m];
        unsigned short hi = f2bf(a);
        rowf[o >> 3][o & 7]       = (short)hi;
        rowf[4 + (o >> 3)][o & 7] = (short)f2bf(a - bf2f(hi));
    }
    #pragma unroll
    for (int ch = 0; ch < 8; ++ch)
        *(short8*)(hT + tid * WP + ch * 8) = rowf[ch];
    __syncthreads();

    // fc1 B-fragments from global (L2-resident 16 KB) — loaded here, not
    // before the point-op (R8 spill lesson)
    int wave = tid >> 6, lane = tid & 63;
    int col = lane & 15, quad = lane >> 4;
    short8 bhi[8], blo[8];
    #pragma unroll
    for (int nt = 0; nt < 8; ++nt) {
        bhi[nt] = *(const short8*)(w1Tg + (size_t)(nt * 16 + col) * 64 + quad * 8);
        blo[nt] = *(const short8*)(w1Tg + (size_t)(nt * 16 + col) * 64 + 32 + quad * 8);
    }
    float lb1r[8], w2r[8];
    #pragma unroll
    for (int nt = 0; nt < 8; ++nt) { lb1r[nt] = b1[nt * 16 + col]; w2r[nt] = w2[nt * 16 + col]; }
    float b2v = b2[0];
    #pragma unroll
    for (int mt = 0; mt < 4; ++mt) {
        int srow = wave * 64 + mt * 16 + col;     // A row m = lane&15
        short8 ahi = *(const short8*)(hT + srow * WP + quad * 8);
        short8 alo = *(const short8*)(hT + srow * WP + 32 + quad * 8);
        float part[4] = {0.f, 0.f, 0.f, 0.f};
        #pragma unroll
        for (int nt = 0; nt < 8; ++nt) {
            floatx4 a = {0.f, 0.f, 0.f, 0.f};
            a = __builtin_amdgcn_mfma_f32_16x16x32_bf16(ahi, bhi[nt], a, 0, 0, 0);
            a = __builtin_amdgcn_mfma_f32_16x16x32_bf16(ahi, blo[nt], a, 0, 0, 0);
            a = __builtin_amdgcn_mfma_f32_16x16x32_bf16(alo, bhi[nt], a, 0, 0, 0);
            #pragma unroll
            for (int r = 0; r < 4; ++r) {
                float t = gelu_fast(a[r] + lb1r[nt]);
                part[r] += t * w2r[nt];
            }
        }
        #pragma unroll
        for (int r = 0; r < 4; ++r) {
            float p = part[r];
            p += __shfl_xor(p, 1, 64);
            p += __shfl_xor(p, 2, 64);
            p += __shfl_xor(p, 4, 64);
            p += __shfl_xor(p, 8, 64);
            if (col == 0) outS[wave * 64 + mt * 16 + quad * 4 + r] = p + b2v;
        }
    }
    __syncthreads();
    out[(size_t)b * SS + blockIdx.x * 256 + tid] = outS[tid];
}

extern "C" void kernel_launch(void* const* d_in, const int* in_sizes, int n_in,
                              void* d_out, int out_size, void* d_ws, size_t ws_size,
                              hipStream_t stream) {
    (void)in_sizes; (void)n_in; (void)out_size; (void)ws_size;
    const float* x    = (const float*)d_in[0];
    const float* pd   = (const float*)d_in[1];
    const float* fc0w = (const float*)d_in[2];
    const float* fc0b = (const float*)d_in[3];
    const float* fc1w = (const float*)d_in[4];
    const float* fc1b = (const float*)d_in[5];
    const float* fc2w = (const float*)d_in[6];
    const float* fc2b = (const float*)d_in[7];

    char* ws = (char*)d_ws;
    float* h = (float*)ws;
    size_t off = (size_t)BB * CC * SS * 4;                            // 167.8 MB
    float* cP = (float*)(ws + off); off += (size_t)4 * NSLOT * BB * 640 * 4;  // 5.24 MB
    float* cA = (float*)(ws + off); off += (size_t)BB * CC * NM * 4;
    float* cB = (float*)(ws + off); off += (size_t)BB * CC * NM * 4;
    float* invmax = (float*)(ws + off); off += 256;
    unsigned short* w1Tg = (unsigned short*)(ws + off); off += (size_t)HH * 64 * 2;  // 16 KB
    const size_t CPL = (size_t)NSLOT * BB * 640;   // floats per layer-slot set

    dim3 gBS(SS / 256, BB);

    k_prep<<<1282, 256, 0, stream>>>(pd, fc1w, invmax, cP, w1Tg);
    k_fc0_dft<<<gBS, 256, 0, stream>>>(x, pd, fc0w, fc0b, invmax, h, cP);

    for (int l = 0; l < 3; ++l) {
        const float* wre = (const float*)d_in[8 + 4 * l];
        const float* wim = (const float*)d_in[9 + 4 * l];
        const float* ww  = (const float*)d_in[10 + 4 * l];
        const float* wb  = (const float*)d_in[11 + 4 * l];
        k_mix<<<BB, 320, 0, stream>>>(cP + (size_t)l * CPL, wre, wim, cA, cB);
        k_point_dft<<<gBS, 256, 0, stream>>>(h, ww, wb, cA, cB,
                                             cP + (size_t)(l + 1) * CPL);
    }
    {   // layer 3 fused with fc1/gelu/fc2
        const float* wre = (const float*)d_in[20];
        const float* wim = (const float*)d_in[21];
        const float* ww  = (const float*)d_in[22];
        const float* wb  = (const float*)d_in[23];
        k_mix<<<BB, 320, 0, stream>>>(cP + (size_t)3 * CPL, wre, wim, cA, cB);
        k_point_final<<<gBS, 256, 0, stream>>>(h, ww, wb, cA, cB,
                                               w1Tg, fc1b, fc2w, fc2b, (float*)d_out);
    }
}